// Round 1
// baseline (313.716 us; speedup 1.0000x reference)
//
#include <hip/hip_runtime.h>
#include <hip/hip_bf16.h>
#include <stdint.h>

#define NN 8192
#define GG 512
#define HH 512
#define LL 64
#define TOPK 9                 // K+1 = 9 (incl. self, self weight zeroed)
#define NEDGE (NN*TOPK)        // 73728 directed edges
#define NNZ (2*NEDGE)          // 147456 CSR entries after symmetrization
#define GRES 32                // spatial grid resolution (cell = 1/32)
#define NCELL (GRES*GRES)
#define LPAD 68                // LDS row pad: 34 dwords == 2 mod 32

typedef unsigned long long u64;
typedef unsigned int u32;
typedef unsigned short u16;

using bf16x8 = __attribute__((ext_vector_type(8))) short;
using f32x4  = __attribute__((ext_vector_type(4))) float;

struct InPtrs { const void* p[12]; };

__device__ __forceinline__ float bf2f(u16 u) { return __uint_as_float(((u32)u) << 16); }
__device__ __forceinline__ u16 f2bf(float f) {
  u32 x = __float_as_uint(f);
  u32 r = x + 0x7fffu + ((x >> 16) & 1u);   // RNE
  return (u16)(r >> 16);
}

// ---------------- inline dtype detection (wave 0 samples 64 u16s of coords) ----------------
__device__ __forceinline__ int detect_isbf(const void* coords_raw, int tid, int* sh) {
  if (tid < 64) {
    float v = bf2f(((const u16*)coords_raw)[tid]);
    bool bad = !(v >= -0.01f && v <= 1.02f);
    u64 bb = __ballot(bad);
    if (tid == 0) *sh = (bb == 0ULL) ? 1 : 0;
  }
  __syncthreads();
  return *sh;
}

// ---------------- convert small tensors + flag + zero deg/cnt + sq (from raw coords) ----------------
__global__ void k_conv_small(InPtrs in, int* __restrict__ flag,
                             float* __restrict__ f32blk, u16* __restrict__ bfblk,
                             float* __restrict__ deg, int* __restrict__ cnt,
                             float* __restrict__ sq) {
  __shared__ int sh;
  const int cnts[11] = {16384, 262144, 512, 1024, 512, 262144, 512, 262144, 512, 32768, 64};
  const int kind[11] = {0, 1, 0, 0, 0, 1, 0, 1, 0, 1, 0};
  const int doff[11] = {0, 0, 16384, 16896, 17920, 262144, 18432, 524288, 18944, 786432, 19456};
  const int TOTAL = 838720;
  int tid = threadIdx.x;
  int isbf = detect_isbf(in.p[1], tid, &sh);
  int gtid = blockIdx.x * blockDim.x + tid;
  if (gtid == 0) *flag = isbf;
  if (gtid < NN) {
    deg[gtid] = 0.0f;
    float x, y;
    if (isbf) { x = bf2f(((const u16*)in.p[1])[2 * gtid]); y = bf2f(((const u16*)in.p[1])[2 * gtid + 1]); }
    else      { x = ((const float*)in.p[1])[2 * gtid];     y = ((const float*)in.p[1])[2 * gtid + 1]; }
    sq[gtid] = __fadd_rn(__fmul_rn(x, x), __fmul_rn(y, y));
  } else if (gtid < 2 * NN) {
    cnt[gtid - NN] = 0;
  }
  for (int e = gtid; e < TOTAL; e += gridDim.x * blockDim.x) {
    int base = 0;
#pragma unroll
    for (int s = 0; s < 11; ++s) {
      if (e < base + cnts[s]) {
        int loc = e - base;
        const void* src = in.p[s + 1];
        float fv = isbf ? bf2f(((const u16*)src)[loc]) : ((const float*)src)[loc];
        if (kind[s] == 0) f32blk[doff[s] + loc] = fv;
        else bfblk[doff[s] + loc] = isbf ? ((const u16*)src)[loc] : f2bf(fv);
        break;
      }
      base += cnts[s];
    }
  }
}

// ---------------- gene -> bf16 ONLY in the fp32-input world ----------------
__global__ void k_conv_gene(const void* __restrict__ src, const void* __restrict__ coords_raw,
                            u32* __restrict__ geneB) {
  __shared__ int sh;
  const int TOTAL = NN * GG / 2;
  int isbf = detect_isbf(coords_raw, threadIdx.x, &sh);
  if (isbf) return;
  for (int e = blockIdx.x * blockDim.x + threadIdx.x; e < TOTAL; e += gridDim.x * blockDim.x) {
    float2 f = ((const float2*)src)[e];
    geneB[e] = (u32)f2bf(f.x) | ((u32)f2bf(f.y) << 16);
  }
}

__device__ __forceinline__ int cell_of(float v) {
  int c = (int)(v * (float)GRES);
  return c < 0 ? 0 : (c > GRES - 1 ? GRES - 1 : c);
}

// ---------------- grid histogram + scan (single block, LDS histogram) ----------------
__global__ __launch_bounds__(1024) void k_grid_scan(const float* __restrict__ coords,
                                                    int* __restrict__ gstart, int* __restrict__ gcur) {
  __shared__ int hist[NCELL];
  int t = threadIdx.x;
  hist[t] = 0;
  __syncthreads();
#pragma unroll
  for (int q = 0; q < 8; ++q) {
    int i = t + 1024 * q;
    int cx = cell_of(coords[2 * i]), cy = cell_of(coords[2 * i + 1]);
    atomicAdd(&hist[cy * GRES + cx], 1);
  }
  __syncthreads();
  int v = hist[t];
  __syncthreads();
  __shared__ int part[NCELL];
  part[t] = v;
  __syncthreads();
  for (int o = 1; o < NCELL; o <<= 1) {
    int add = 0;
    if (t >= o) add = part[t - o];
    __syncthreads();
    part[t] += add;
    __syncthreads();
  }
  int excl = part[t] - v;
  gstart[t] = excl;
  gcur[t] = excl;
  if (t == NCELL - 1) gstart[NCELL] = part[t];
}

__global__ void k_grid_fill(const float* __restrict__ coords, const float* __restrict__ sq,
                            int* __restrict__ gcur, float4* __restrict__ pts) {
  int i = blockIdx.x * blockDim.x + threadIdx.x;
  if (i < NN) {
    float x = coords[2*i], y = coords[2*i+1];
    int cx = cell_of(x), cy = cell_of(y);
    int p = atomicAdd(&gcur[cy * GRES + cx], 1);
    pts[p] = make_float4(x, y, sq[i], __int_as_float(i));
  }
}

// ---------------- KNN top-9 via spatial grid (exact; inline full-scan fallback) ----------------
__global__ __launch_bounds__(256) void k_knn_grid(const float4* __restrict__ pts,
                                                  const int* __restrict__ gstart,
                                                  const float* __restrict__ coords,
                                                  const float* __restrict__ sq,
                                                  int* __restrict__ eidx, float* __restrict__ ew) {
  const int w = threadIdx.x >> 6, lane = threadIdx.x & 63;
  const int i = blockIdx.x * 4 + w;
  const float qx = coords[2*i], qy = coords[2*i+1];
  const float sqi = sq[i];
  const int cx = cell_of(qx), cy = cell_of(qy);
  const int x0 = max(cx - 2, 0), x1 = min(cx + 2, GRES - 1);
  const int y0 = max(cy - 2, 0), y1 = min(cy + 2, GRES - 1);

  u64 a0 = ~0ULL, a1 = ~0ULL, a2 = ~0ULL, a3 = ~0ULL, a4 = ~0ULL,
      a5 = ~0ULL, a6 = ~0ULL, a7 = ~0ULL, a8 = ~0ULL;

#define KSTEP(A) { u64 t_ = A; bool p_ = x < t_; A = p_ ? x : t_; x = p_ ? t_ : x; }
  for (int yy = y0; yy <= y1; ++yy) {
    int sbeg = gstart[yy * GRES + x0];
    int send = gstart[yy * GRES + x1 + 1];
    for (int p = sbeg + lane; p < send; p += 64) {
      float4 pt = pts[p];
      float dot = __fmaf_rn(qy, pt.y, __fmul_rn(qx, pt.x));
      float d2  = __fsub_rn(__fadd_rn(sqi, pt.z), __fmul_rn(2.0f, dot));
      float d   = __fsqrt_rn(fmaxf(d2, 0.0f));
      u64 x = ((u64)__float_as_uint(d) << 32) | (u32)__float_as_int(pt.w);
      KSTEP(a0) KSTEP(a1) KSTEP(a2) KSTEP(a3) KSTEP(a4)
      KSTEP(a5) KSTEP(a6) KSTEP(a7) KSTEP(a8)
    }
  }

  u64 g9 = ~0ULL;
  for (int r = 0; r < TOPK; ++r) {
    u64 g = a0;
#pragma unroll
    for (int o = 32; o > 0; o >>= 1) {
      u64 other = __shfl_xor(g, o, 64);
      if (other < g) g = other;
    }
    bool own = (a0 == g);
    a0 = own ? a1 : a0;  a1 = own ? a2 : a1;  a2 = own ? a3 : a2;
    a3 = own ? a4 : a3;  a4 = own ? a5 : a4;  a5 = own ? a6 : a5;
    a6 = own ? a7 : a6;  a7 = own ? a8 : a7;  a8 = own ? ~0ULL : a8;
    g9 = g;
    if (lane == 0) {
      u32 dbits = (u32)(g >> 32);
      int j = (int)(g & 0xffffffffu);
      float d = __uint_as_float(dbits);
      float wgt = (j == i) ? 0.0f : expf(__fdiv_rn(-__fmul_rn(d, d), 2.0f));
      eidx[i * TOPK + r] = j;
      ew[i * TOPK + r] = wgt;
    }
  }

  float d9 = __uint_as_float((u32)(g9 >> 32));
  if (!(d9 < 0.0624f)) {
    a0 = a1 = a2 = a3 = a4 = a5 = a6 = a7 = a8 = ~0ULL;
    const float2* c2 = (const float2*)coords;
    for (int c = 0; c < 128; ++c) {
      int j = c * 64 + lane;
      float2 cjf = c2[j];
      float dot = __fmaf_rn(qy, cjf.y, __fmul_rn(qx, cjf.x));
      float d2  = __fsub_rn(__fadd_rn(sqi, sq[j]), __fmul_rn(2.0f, dot));
      float d   = __fsqrt_rn(fmaxf(d2, 0.0f));
      u64 x = ((u64)__float_as_uint(d) << 32) | (u32)j;
      KSTEP(a0) KSTEP(a1) KSTEP(a2) KSTEP(a3) KSTEP(a4)
      KSTEP(a5) KSTEP(a6) KSTEP(a7) KSTEP(a8)
    }
    for (int r = 0; r < TOPK; ++r) {
      u64 g = a0;
#pragma unroll
      for (int o = 32; o > 0; o >>= 1) {
        u64 other = __shfl_xor(g, o, 64);
        if (other < g) g = other;
      }
      bool own = (a0 == g);
      a0 = own ? a1 : a0;  a1 = own ? a2 : a1;  a2 = own ? a3 : a2;
      a3 = own ? a4 : a3;  a4 = own ? a5 : a4;  a5 = own ? a6 : a5;
      a6 = own ? a7 : a6;  a7 = own ? a8 : a7;  a8 = own ? ~0ULL : a8;
      if (lane == 0) {
        u32 dbits = (u32)(g >> 32);
        int j = (int)(g & 0xffffffffu);
        float d = __uint_as_float(dbits);
        float wgt = (j == i) ? 0.0f : expf(__fdiv_rn(-__fmul_rn(d, d), 2.0f));
        eidx[i * TOPK + r] = j;
        ew[i * TOPK + r] = wgt;
      }
    }
  }
#undef KSTEP
}

// ---------------- fused degree + count ----------------
__global__ void k_degcnt(const int* __restrict__ eidx, const float* __restrict__ ew,
                         float* __restrict__ deg, int* __restrict__ cnt) {
  int t = blockIdx.x * blockDim.x + threadIdx.x;
  if (t >= NEDGE) return;
  int i = t / TOPK;
  int j = eidx[t] & (NN - 1);
  float h = 0.5f * ew[t];
  atomicAdd(&deg[i], h);
  atomicAdd(&deg[j], h);
  atomicAdd(&cnt[i], 1);
  atomicAdd(&cnt[j], 1);
}

// ---------------- CSR scan (+ dis from deg) ----------------
__global__ __launch_bounds__(1024) void k_scan(const int* __restrict__ cnt,
                                               const float* __restrict__ deg,
                                               int* __restrict__ rs, int* __restrict__ cur,
                                               float* __restrict__ dis) {
  __shared__ int part[1024];
  int t = threadIdx.x;
  int base = t * 8;
  int loc[8]; int s = 0;
#pragma unroll
  for (int q = 0; q < 8; ++q) { loc[q] = s; s += cnt[base + q]; }
  part[t] = s;
  __syncthreads();
  for (int o = 1; o < 1024; o <<= 1) {
    int v = 0;
    if (t >= o) v = part[t - o];
    __syncthreads();
    part[t] += v;
    __syncthreads();
  }
  int excl = (t == 0) ? 0 : part[t - 1];
#pragma unroll
  for (int q = 0; q < 8; ++q) {
    int val = excl + loc[q];
    rs[base + q] = val;
    cur[base + q] = val;
    dis[base + q] = 1.0f / sqrtf(deg[base + q] + 1e-8f);
  }
  if (t == 1023) rs[NN] = excl + s;
}

__global__ void k_fill(const int* __restrict__ eidx, const float* __restrict__ ew,
                       int* __restrict__ cur, int* __restrict__ ccol, float* __restrict__ cw) {
  int t = blockIdx.x * blockDim.x + threadIdx.x;
  if (t >= NEDGE) return;
  int i = t / TOPK;
  int j = eidx[t] & (NN - 1);
  float h = 0.5f * ew[t];
  int s1 = atomicAdd(&cur[i], 1); ccol[s1] = j; cw[s1] = h;
  int s2 = atomicAdd(&cur[j], 1); ccol[s2] = i; cw[s2] = h;
}

// ---------------- agg = A_norm @ h (bf16 in/out; packed u32 stores) ----------------
__global__ __launch_bounds__(256) void k_agg(const int* __restrict__ rs, const int* __restrict__ ccol,
                                             const float* __restrict__ cw, const float* __restrict__ dis,
                                             const u16* __restrict__ h, u16* __restrict__ agg) {
  int i = blockIdx.x, t = threadIdx.x;
  int b = rs[i], e = rs[i + 1];
  float di = dis[i];
  float s0 = 0.f, s1 = 0.f;
  for (int q = b; q < e; ++q) {
    int c = ccol[q];
    float w = cw[q] * dis[c];
    u32 p = *(const u32*)(h + (size_t)c * HH + 2 * t);
    s0 = fmaf(w, bf2f((u16)(p & 0xffff)), s0);
    s1 = fmaf(w, bf2f((u16)(p >> 16)), s1);
  }
  u32 packed = (u32)f2bf(di * s0) | ((u32)f2bf(di * s1) << 16);
  *(u32*)(agg + (size_t)i * HH + 2 * t) = packed;
}

// ---------------- MFMA bf16 GEMM, BM=128: C = A[M,512]*W[C,512]^T ----------------
// Epilogue: stage [128][64] bf16 tile in LDS (reusing As), then bulk uint4 stores so
// every 128B output line is written whole by one wave instruction (kills the 9.4x
// write amplification the scalar u16 scatter stores caused at TCC).
template <int MODE>
__global__ __launch_bounds__(256) void k_mgemm(const void* __restrict__ Araw, const u16* __restrict__ Aconv,
                                               const u16* __restrict__ W,
                                               const float* __restrict__ bias,
                                               const float* __restrict__ coords,
                                               const float* __restrict__ Wc1, const float* __restrict__ bc1,
                                               const int* __restrict__ flag,
                                               void* __restrict__ outp, int ldc) {
  __shared__ u16 As[128][LPAD];
  __shared__ u16 Bs[64][LPAD];
  const int tid = threadIdx.x, lane = tid & 63, w = tid >> 6;
  const int quad = lane >> 4, l16 = lane & 15;
  const int row0 = blockIdx.x * 128, col0 = blockIdx.y * 64;

  int flg = *flag;
  const u16* A = (MODE == 0) ? ((flg ? (const u16*)Araw : Aconv)) : Aconv;

  f32x4 acc[2][4];
#pragma unroll
  for (int mr = 0; mr < 2; ++mr)
#pragma unroll
    for (int n = 0; n < 4; ++n) acc[mr][n] = (f32x4){0.f, 0.f, 0.f, 0.f};

  const int r_ld = tid >> 3, c8_ld = (tid & 7) * 8;

  for (int kk = 0; kk < 512; kk += 64) {
    uint4 av[4]; uint4 bv[2];
#pragma unroll
    for (int q = 0; q < 4; ++q)
      av[q] = *(const uint4*)(A + (size_t)(row0 + r_ld + 32 * q) * 512 + kk + c8_ld);
#pragma unroll
    for (int q = 0; q < 2; ++q)
      bv[q] = *(const uint4*)(W + (size_t)(col0 + r_ld + 32 * q) * 512 + kk + c8_ld);
    __syncthreads();
#pragma unroll
    for (int q = 0; q < 4; ++q)
      *(uint4*)(&As[r_ld + 32 * q][c8_ld]) = av[q];
#pragma unroll
    for (int q = 0; q < 2; ++q)
      *(uint4*)(&Bs[r_ld + 32 * q][c8_ld]) = bv[q];
    __syncthreads();
#pragma unroll
    for (int kc = 0; kc < 2; ++kc) {
      bf16x8 af[2], bfr[4];
#pragma unroll
      for (int mr = 0; mr < 2; ++mr)
        af[mr] = *(const bf16x8*)(&As[w * 32 + mr * 16 + l16][kc * 32 + quad * 8]);
#pragma unroll
      for (int n = 0; n < 4; ++n)
        bfr[n] = *(const bf16x8*)(&Bs[n * 16 + l16][kc * 32 + quad * 8]);
#pragma unroll
      for (int mr = 0; mr < 2; ++mr)
#pragma unroll
        for (int n = 0; n < 4; ++n)
          acc[mr][n] = __builtin_amdgcn_mfma_f32_16x16x32_bf16(af[mr], bfr[n], acc[mr][n], 0, 0, 0);
    }
  }

  if (MODE == 3 && !flg) {
    // fp32-output path: keep dword scalar stores (full sectors, rare path)
#pragma unroll
    for (int mr = 0; mr < 2; ++mr) {
      int rbase = row0 + w * 32 + mr * 16 + quad * 4;
#pragma unroll
      for (int n = 0; n < 4; ++n) {
        int cg = col0 + n * 16 + l16;
        float bval = bias[cg];
#pragma unroll
        for (int reg = 0; reg < 4; ++reg) {
          int rg = rbase + reg;
          ((float*)outp)[(size_t)rg * ldc + cg] = acc[mr][n][reg] + bval;
        }
      }
    }
    return;
  }

  __syncthreads();                 // protect As from reuse while MFMA ds_reads drain
  u16* St = &As[0][0];             // [128][64] staging tile (8192 u16 <= 128*LPAD)
#pragma unroll
  for (int mr = 0; mr < 2; ++mr) {
    int rloc = w * 32 + mr * 16 + quad * 4;
    int rbase = row0 + rloc;
    float cx[4], cy[4];
    if (MODE == 0) {
#pragma unroll
      for (int reg = 0; reg < 4; ++reg) { cx[reg] = coords[2 * (rbase + reg)]; cy[reg] = coords[2 * (rbase + reg) + 1]; }
    }
#pragma unroll
    for (int n = 0; n < 4; ++n) {
      int cg = col0 + n * 16 + l16;
      float bval = bias[cg];
      float wc0 = 0.f, wc1 = 0.f, bcv = 0.f;
      if (MODE == 0) { wc0 = Wc1[2 * cg]; wc1 = Wc1[2 * cg + 1]; bcv = bc1[cg]; }
#pragma unroll
      for (int reg = 0; reg < 4; ++reg) {
        float v = acc[mr][n][reg] + bval;
        if (MODE == 0) {
          float hc = cx[reg] * wc0 + cy[reg] * wc1 + bcv;
          v = fmaxf(v, 0.f) + fmaxf(hc, 0.f);
        }
        St[(rloc + reg) * 64 + n * 16 + l16] = f2bf(v);
      }
    }
  }
  __syncthreads();
  // 1024 uint4 chunks: 8 lanes cover one full 128B output line
#pragma unroll
  for (int q = 0; q < 4; ++q) {
    int idx = tid + 256 * q;
    int r = idx >> 3, c = idx & 7;
    *(uint4*)((u16*)outp + (size_t)(row0 + r) * ldc + col0 + c * 8) = ((const uint4*)St)[idx];
  }
}

// ---------------- FUSED GEMM2+3 (dual-stream, BM=128) ----------------
// Occupancy cap removed: the 2-blocks/CU cap existed only to limit the write
// amplification of the scalar u16 scatter epilogue. With the LDS-staged
// full-line epilogue, writes stay ~= output size, so run at natural 3 blocks/CU
// (LDS 51 KB) for better latency hiding.
__global__ __launch_bounds__(256) void k_mgemm23(const u16* __restrict__ A1, const u16* __restrict__ W1,
                                                 const float* __restrict__ b1,
                                                 const u16* __restrict__ A2, const u16* __restrict__ W2,
                                                 const float* __restrict__ b2,
                                                 u16* __restrict__ outp) {
  __shared__ u16 As1[128][LPAD];
  __shared__ u16 As2[128][LPAD];
  __shared__ u16 Bs1[64][LPAD];
  __shared__ u16 Bs2[64][LPAD];
  const int tid = threadIdx.x, lane = tid & 63, w = tid >> 6;
  const int quad = lane >> 4, l16 = lane & 15;
  const int row0 = blockIdx.x * 128, col0 = blockIdx.y * 64;

  f32x4 acc1[2][4], acc2[2][4];
#pragma unroll
  for (int mr = 0; mr < 2; ++mr)
#pragma unroll
    for (int n = 0; n < 4; ++n) {
      acc1[mr][n] = (f32x4){0.f, 0.f, 0.f, 0.f};
      acc2[mr][n] = (f32x4){0.f, 0.f, 0.f, 0.f};
    }

  const int r_ld = tid >> 3, c8_ld = (tid & 7) * 8;

  for (int kk = 0; kk < 512; kk += 64) {
    uint4 av1[4], av2[4], bv1[2], bv2[2];
#pragma unroll
    for (int q = 0; q < 4; ++q) {
      av1[q] = *(const uint4*)(A1 + (size_t)(row0 + r_ld + 32 * q) * 512 + kk + c8_ld);
      av2[q] = *(const uint4*)(A2 + (size_t)(row0 + r_ld + 32 * q) * 512 + kk + c8_ld);
    }
#pragma unroll
    for (int q = 0; q < 2; ++q) {
      bv1[q] = *(const uint4*)(W1 + (size_t)(col0 + r_ld + 32 * q) * 512 + kk + c8_ld);
      bv2[q] = *(const uint4*)(W2 + (size_t)(col0 + r_ld + 32 * q) * 512 + kk + c8_ld);
    }
    __syncthreads();
#pragma unroll
    for (int q = 0; q < 4; ++q) {
      *(uint4*)(&As1[r_ld + 32 * q][c8_ld]) = av1[q];
      *(uint4*)(&As2[r_ld + 32 * q][c8_ld]) = av2[q];
    }
#pragma unroll
    for (int q = 0; q < 2; ++q) {
      *(uint4*)(&Bs1[r_ld + 32 * q][c8_ld]) = bv1[q];
      *(uint4*)(&Bs2[r_ld + 32 * q][c8_ld]) = bv2[q];
    }
    __syncthreads();
#pragma unroll
    for (int kc = 0; kc < 2; ++kc) {
      bf16x8 af1[2], af2[2], bf1[4], bf2[4];
#pragma unroll
      for (int mr = 0; mr < 2; ++mr) {
        af1[mr] = *(const bf16x8*)(&As1[w * 32 + mr * 16 + l16][kc * 32 + quad * 8]);
        af2[mr] = *(const bf16x8*)(&As2[w * 32 + mr * 16 + l16][kc * 32 + quad * 8]);
      }
#pragma unroll
      for (int n = 0; n < 4; ++n) {
        bf1[n] = *(const bf16x8*)(&Bs1[n * 16 + l16][kc * 32 + quad * 8]);
        bf2[n] = *(const bf16x8*)(&Bs2[n * 16 + l16][kc * 32 + quad * 8]);
      }
#pragma unroll
      for (int mr = 0; mr < 2; ++mr)
#pragma unroll
        for (int n = 0; n < 4; ++n) {
          acc1[mr][n] = __builtin_amdgcn_mfma_f32_16x16x32_bf16(af1[mr], bf1[n], acc1[mr][n], 0, 0, 0);
          acc2[mr][n] = __builtin_amdgcn_mfma_f32_16x16x32_bf16(af2[mr], bf2[n], acc2[mr][n], 0, 0, 0);
        }
    }
  }

  __syncthreads();                 // protect As1 from reuse while MFMA ds_reads drain
  u16* St = &As1[0][0];            // [128][64] staging tile
#pragma unroll
  for (int mr = 0; mr < 2; ++mr) {
    int rloc = w * 32 + mr * 16 + quad * 4;
#pragma unroll
    for (int n = 0; n < 4; ++n) {
      int cg = col0 + n * 16 + l16;
      float bv1 = b1[cg], bv2 = b2[cg];
#pragma unroll
      for (int reg = 0; reg < 4; ++reg) {
        float msg  = fmaxf(acc1[mr][n][reg] + bv1, 0.f);
        float self = fmaxf(acc2[mr][n][reg] + bv2, 0.f);
        St[(rloc + reg) * 64 + n * 16 + l16] = f2bf(fmaxf(msg + self, 0.f));
      }
    }
  }
  __syncthreads();
#pragma unroll
  for (int q = 0; q < 4; ++q) {
    int idx = tid + 256 * q;
    int r = idx >> 3, c = idx & 7;
    *(uint4*)(outp + (size_t)(row0 + r) * 512 + col0 + c * 8) = ((const uint4*)St)[idx];
  }
}

extern "C" void kernel_launch(void* const* d_in, const int* in_sizes, int n_in,
                              void* d_out, int out_size, void* d_ws, size_t ws_size,
                              hipStream_t stream) {
  float* ws = (float*)d_ws;
  size_t off = 0;
  auto alloc = [&](size_t n) { size_t o = off; off += (n + 15) & ~(size_t)15; return o; };

  const size_t PLANE = (size_t)NN * HH / 2;

  size_t o_flag  = alloc(16);
  size_t o_f32   = alloc(19520);
  size_t o_bfw   = alloc(409600);
  size_t o_geneB = alloc(PLANE);
  size_t o_Hb    = alloc(PLANE);
  size_t o_Mb    = alloc(PLANE);
  size_t o_sq    = alloc(NN);
  size_t o_deg   = alloc(NN);
  size_t o_dis   = alloc(NN);
  size_t o_cnt   = alloc(NN);
  size_t o_rs    = alloc(NN + 16);
  size_t o_cur   = alloc(NN);
  size_t o_eidx  = alloc(NEDGE);
  size_t o_ew    = alloc(NEDGE);
  size_t o_ccol  = alloc(NNZ);
  size_t o_cw    = alloc(NNZ);
  size_t o_pts   = alloc(NN * 4);
  size_t o_gsta  = alloc(NCELL + 16);
  size_t o_gcur  = alloc(NCELL);
  (void)ws_size;

  int*   flag    = (int*)(ws + o_flag);
  float* f32blk  = ws + o_f32;
  float* coordsF = f32blk + 0;
  float* bg1     = f32blk + 16384;
  float* Wc1f    = f32blk + 16896;
  float* bc1f    = f32blk + 17920;
  float* bmsg    = f32blk + 18432;
  float* bself   = f32blk + 18944;
  float* bz      = f32blk + 19456;
  u16*   bfblk   = (u16*)(ws + o_bfw);
  u16*   WgB     = bfblk + 0;
  u16*   WmB     = bfblk + 262144;
  u16*   WsB     = bfblk + 524288;
  u16*   WzB     = bfblk + 786432;
  u16*   geneB   = (u16*)(ws + o_geneB);
  u16*   AGGB    = geneB;
  u16*   Hb      = (u16*)(ws + o_Hb);
  u16*   Mb      = (u16*)(ws + o_Mb);
  float* sq      = ws + o_sq;
  float* deg     = ws + o_deg;
  float* dis     = ws + o_dis;
  int*   cnt     = (int*)(ws + o_cnt);
  int*   rs      = (int*)(ws + o_rs);
  int*   cur     = (int*)(ws + o_cur);
  int*   eidx    = (int*)(ws + o_eidx);
  float* ew      = ws + o_ew;
  int*   ccol    = (int*)(ws + o_ccol);
  float* cw      = ws + o_cw;
  float4* pts    = (float4*)(ws + o_pts);
  int*   gstart  = (int*)(ws + o_gsta);
  int*   gcur    = (int*)(ws + o_gcur);

  InPtrs ip;
  for (int s = 0; s < 12; ++s) ip.p[s] = d_in[s];

  k_conv_small<<<512, 256, 0, stream>>>(ip, flag, f32blk, bfblk, deg, cnt, sq);
  k_conv_gene<<<2048, 256, 0, stream>>>(d_in[0], d_in[1], (u32*)geneB);
  k_grid_scan<<<1, 1024, 0, stream>>>(coordsF, gstart, gcur);
  k_grid_fill<<<NN / 256, 256, 0, stream>>>(coordsF, sq, gcur, pts);
  k_knn_grid<<<NN / 4, 256, 0, stream>>>(pts, gstart, coordsF, sq, eidx, ew);
  k_degcnt<<<(NEDGE + 255) / 256, 256, 0, stream>>>(eidx, ew, deg, cnt);
  k_scan<<<1, 1024, 0, stream>>>(cnt, deg, rs, cur, dis);
  k_fill<<<(NEDGE + 255) / 256, 256, 0, stream>>>(eidx, ew, cur, ccol, cw);

  dim3 blk(256);
  k_mgemm<0><<<dim3(64, 8), blk, 0, stream>>>(d_in[0], geneB, WgB, bg1, coordsF, Wc1f, bc1f, flag, Hb, 512);
  k_agg<<<NN, 256, 0, stream>>>(rs, ccol, cw, dis, Hb, AGGB);
  k_mgemm23<<<dim3(64, 8), blk, 0, stream>>>(AGGB, WmB, bmsg, Hb, WsB, bself, Mb);
  k_mgemm<3><<<dim3(64, 1), blk, 0, stream>>>(nullptr, Mb, WzB, bz, nullptr, nullptr, nullptr, flag, d_out, 64);
}

// Round 2
// 232.736 us; speedup vs baseline: 1.3479x; 1.3479x over previous
//
#include <hip/hip_runtime.h>
#include <hip/hip_bf16.h>
#include <stdint.h>

#define NN 8192
#define GG 512
#define HH 512
#define LL 64
#define TOPK 9                 // K+1 = 9 (incl. self, self weight zeroed)
#define NEDGE (NN*TOPK)        // 73728 directed edges
#define NNZ (2*NEDGE)          // 147456 CSR entries after symmetrization
#define GRES 32                // spatial grid resolution (cell = 1/32)
#define NCELL (GRES*GRES)
#define BPAD 516               // LDS B-panel row pad: 258 dwords == 2 mod 32 (conflict-free class)

typedef unsigned long long u64;
typedef unsigned int u32;
typedef unsigned short u16;

using bf16x8 = __attribute__((ext_vector_type(8))) short;
using f32x4  = __attribute__((ext_vector_type(4))) float;

struct InPtrs { const void* p[12]; };

__device__ __forceinline__ float bf2f(u16 u) { return __uint_as_float(((u32)u) << 16); }
__device__ __forceinline__ u16 f2bf(float f) {
  u32 x = __float_as_uint(f);
  u32 r = x + 0x7fffu + ((x >> 16) & 1u);   // RNE
  return (u16)(r >> 16);
}

// ---------------- inline dtype detection (wave 0 samples 64 u16s of coords) ----------------
__device__ __forceinline__ int detect_isbf(const void* coords_raw, int tid, int* sh) {
  if (tid < 64) {
    float v = bf2f(((const u16*)coords_raw)[tid]);
    bool bad = !(v >= -0.01f && v <= 1.02f);
    u64 bb = __ballot(bad);
    if (tid == 0) *sh = (bb == 0ULL) ? 1 : 0;
  }
  __syncthreads();
  return *sh;
}

// ---------------- convert small tensors + flag + zero deg/cnt + sq (from raw coords) ----------------
__global__ void k_conv_small(InPtrs in, int* __restrict__ flag,
                             float* __restrict__ f32blk, u16* __restrict__ bfblk,
                             float* __restrict__ deg, int* __restrict__ cnt,
                             float* __restrict__ sq) {
  __shared__ int sh;
  const int cnts[11] = {16384, 262144, 512, 1024, 512, 262144, 512, 262144, 512, 32768, 64};
  const int kind[11] = {0, 1, 0, 0, 0, 1, 0, 1, 0, 1, 0};
  const int doff[11] = {0, 0, 16384, 16896, 17920, 262144, 18432, 524288, 18944, 786432, 19456};
  const int TOTAL = 838720;
  int tid = threadIdx.x;
  int isbf = detect_isbf(in.p[1], tid, &sh);
  int gtid = blockIdx.x * blockDim.x + tid;
  if (gtid == 0) *flag = isbf;
  if (gtid < NN) {
    deg[gtid] = 0.0f;
    float x, y;
    if (isbf) { x = bf2f(((const u16*)in.p[1])[2 * gtid]); y = bf2f(((const u16*)in.p[1])[2 * gtid + 1]); }
    else      { x = ((const float*)in.p[1])[2 * gtid];     y = ((const float*)in.p[1])[2 * gtid + 1]; }
    sq[gtid] = __fadd_rn(__fmul_rn(x, x), __fmul_rn(y, y));
  } else if (gtid < 2 * NN) {
    cnt[gtid - NN] = 0;
  }
  for (int e = gtid; e < TOTAL; e += gridDim.x * blockDim.x) {
    int base = 0;
#pragma unroll
    for (int s = 0; s < 11; ++s) {
      if (e < base + cnts[s]) {
        int loc = e - base;
        const void* src = in.p[s + 1];
        float fv = isbf ? bf2f(((const u16*)src)[loc]) : ((const float*)src)[loc];
        if (kind[s] == 0) f32blk[doff[s] + loc] = fv;
        else bfblk[doff[s] + loc] = isbf ? ((const u16*)src)[loc] : f2bf(fv);
        break;
      }
      base += cnts[s];
    }
  }
}

// ---------------- gene -> bf16 ONLY in the fp32-input world ----------------
__global__ void k_conv_gene(const void* __restrict__ src, const void* __restrict__ coords_raw,
                            u32* __restrict__ geneB) {
  __shared__ int sh;
  const int TOTAL = NN * GG / 2;
  int isbf = detect_isbf(coords_raw, threadIdx.x, &sh);
  if (isbf) return;
  for (int e = blockIdx.x * blockDim.x + threadIdx.x; e < TOTAL; e += gridDim.x * blockDim.x) {
    float2 f = ((const float2*)src)[e];
    geneB[e] = (u32)f2bf(f.x) | ((u32)f2bf(f.y) << 16);
  }
}

__device__ __forceinline__ int cell_of(float v) {
  int c = (int)(v * (float)GRES);
  return c < 0 ? 0 : (c > GRES - 1 ? GRES - 1 : c);
}

// ---------------- grid histogram + scan (single block, LDS histogram) ----------------
__global__ __launch_bounds__(1024) void k_grid_scan(const float* __restrict__ coords,
                                                    int* __restrict__ gstart, int* __restrict__ gcur) {
  __shared__ int hist[NCELL];
  int t = threadIdx.x;
  hist[t] = 0;
  __syncthreads();
#pragma unroll
  for (int q = 0; q < 8; ++q) {
    int i = t + 1024 * q;
    int cx = cell_of(coords[2 * i]), cy = cell_of(coords[2 * i + 1]);
    atomicAdd(&hist[cy * GRES + cx], 1);
  }
  __syncthreads();
  int v = hist[t];
  __syncthreads();
  __shared__ int part[NCELL];
  part[t] = v;
  __syncthreads();
  for (int o = 1; o < NCELL; o <<= 1) {
    int add = 0;
    if (t >= o) add = part[t - o];
    __syncthreads();
    part[t] += add;
    __syncthreads();
  }
  int excl = part[t] - v;
  gstart[t] = excl;
  gcur[t] = excl;
  if (t == NCELL - 1) gstart[NCELL] = part[t];
}

__global__ void k_grid_fill(const float* __restrict__ coords, const float* __restrict__ sq,
                            int* __restrict__ gcur, float4* __restrict__ pts) {
  int i = blockIdx.x * blockDim.x + threadIdx.x;
  if (i < NN) {
    float x = coords[2*i], y = coords[2*i+1];
    int cx = cell_of(x), cy = cell_of(y);
    int p = atomicAdd(&gcur[cy * GRES + cx], 1);
    pts[p] = make_float4(x, y, sq[i], __int_as_float(i));
  }
}

// ---------------- KNN top-9 via spatial grid (exact; inline full-scan fallback) ----------------
__global__ __launch_bounds__(256) void k_knn_grid(const float4* __restrict__ pts,
                                                  const int* __restrict__ gstart,
                                                  const float* __restrict__ coords,
                                                  const float* __restrict__ sq,
                                                  int* __restrict__ eidx, float* __restrict__ ew) {
  const int w = threadIdx.x >> 6, lane = threadIdx.x & 63;
  const int i = blockIdx.x * 4 + w;
  const float qx = coords[2*i], qy = coords[2*i+1];
  const float sqi = sq[i];
  const int cx = cell_of(qx), cy = cell_of(qy);
  const int x0 = max(cx - 2, 0), x1 = min(cx + 2, GRES - 1);
  const int y0 = max(cy - 2, 0), y1 = min(cy + 2, GRES - 1);

  u64 a0 = ~0ULL, a1 = ~0ULL, a2 = ~0ULL, a3 = ~0ULL, a4 = ~0ULL,
      a5 = ~0ULL, a6 = ~0ULL, a7 = ~0ULL, a8 = ~0ULL;

#define KSTEP(A) { u64 t_ = A; bool p_ = x < t_; A = p_ ? x : t_; x = p_ ? t_ : x; }
  for (int yy = y0; yy <= y1; ++yy) {
    int sbeg = gstart[yy * GRES + x0];
    int send = gstart[yy * GRES + x1 + 1];
    for (int p = sbeg + lane; p < send; p += 64) {
      float4 pt = pts[p];
      float dot = __fmaf_rn(qy, pt.y, __fmul_rn(qx, pt.x));
      float d2  = __fsub_rn(__fadd_rn(sqi, pt.z), __fmul_rn(2.0f, dot));
      float d   = __fsqrt_rn(fmaxf(d2, 0.0f));
      u64 x = ((u64)__float_as_uint(d) << 32) | (u32)__float_as_int(pt.w);
      KSTEP(a0) KSTEP(a1) KSTEP(a2) KSTEP(a3) KSTEP(a4)
      KSTEP(a5) KSTEP(a6) KSTEP(a7) KSTEP(a8)
    }
  }

  u64 g9 = ~0ULL;
  for (int r = 0; r < TOPK; ++r) {
    u64 g = a0;
#pragma unroll
    for (int o = 32; o > 0; o >>= 1) {
      u64 other = __shfl_xor(g, o, 64);
      if (other < g) g = other;
    }
    bool own = (a0 == g);
    a0 = own ? a1 : a0;  a1 = own ? a2 : a1;  a2 = own ? a3 : a2;
    a3 = own ? a4 : a3;  a4 = own ? a5 : a4;  a5 = own ? a6 : a5;
    a6 = own ? a7 : a6;  a7 = own ? a8 : a7;  a8 = own ? ~0ULL : a8;
    g9 = g;
    if (lane == 0) {
      u32 dbits = (u32)(g >> 32);
      int j = (int)(g & 0xffffffffu);
      float d = __uint_as_float(dbits);
      float wgt = (j == i) ? 0.0f : expf(__fdiv_rn(-__fmul_rn(d, d), 2.0f));
      eidx[i * TOPK + r] = j;
      ew[i * TOPK + r] = wgt;
    }
  }

  float d9 = __uint_as_float((u32)(g9 >> 32));
  if (!(d9 < 0.0624f)) {
    a0 = a1 = a2 = a3 = a4 = a5 = a6 = a7 = a8 = ~0ULL;
    const float2* c2 = (const float2*)coords;
    for (int c = 0; c < 128; ++c) {
      int j = c * 64 + lane;
      float2 cjf = c2[j];
      float dot = __fmaf_rn(qy, cjf.y, __fmul_rn(qx, cjf.x));
      float d2  = __fsub_rn(__fadd_rn(sqi, sq[j]), __fmul_rn(2.0f, dot));
      float d   = __fsqrt_rn(fmaxf(d2, 0.0f));
      u64 x = ((u64)__float_as_uint(d) << 32) | (u32)j;
      KSTEP(a0) KSTEP(a1) KSTEP(a2) KSTEP(a3) KSTEP(a4)
      KSTEP(a5) KSTEP(a6) KSTEP(a7) KSTEP(a8)
    }
    for (int r = 0; r < TOPK; ++r) {
      u64 g = a0;
#pragma unroll
      for (int o = 32; o > 0; o >>= 1) {
        u64 other = __shfl_xor(g, o, 64);
        if (other < g) g = other;
      }
      bool own = (a0 == g);
      a0 = own ? a1 : a0;  a1 = own ? a2 : a1;  a2 = own ? a3 : a2;
      a3 = own ? a4 : a3;  a4 = own ? a5 : a4;  a5 = own ? a6 : a5;
      a6 = own ? a7 : a6;  a7 = own ? a8 : a7;  a8 = own ? ~0ULL : a8;
      if (lane == 0) {
        u32 dbits = (u32)(g >> 32);
        int j = (int)(g & 0xffffffffu);
        float d = __uint_as_float(dbits);
        float wgt = (j == i) ? 0.0f : expf(__fdiv_rn(-__fmul_rn(d, d), 2.0f));
        eidx[i * TOPK + r] = j;
        ew[i * TOPK + r] = wgt;
      }
    }
  }
#undef KSTEP
}

// ---------------- fused degree + count ----------------
__global__ void k_degcnt(const int* __restrict__ eidx, const float* __restrict__ ew,
                         float* __restrict__ deg, int* __restrict__ cnt) {
  int t = blockIdx.x * blockDim.x + threadIdx.x;
  if (t >= NEDGE) return;
  int i = t / TOPK;
  int j = eidx[t] & (NN - 1);
  float h = 0.5f * ew[t];
  atomicAdd(&deg[i], h);
  atomicAdd(&deg[j], h);
  atomicAdd(&cnt[i], 1);
  atomicAdd(&cnt[j], 1);
}

// ---------------- CSR scan (+ dis from deg) ----------------
__global__ __launch_bounds__(1024) void k_scan(const int* __restrict__ cnt,
                                               const float* __restrict__ deg,
                                               int* __restrict__ rs, int* __restrict__ cur,
                                               float* __restrict__ dis) {
  __shared__ int part[1024];
  int t = threadIdx.x;
  int base = t * 8;
  int loc[8]; int s = 0;
#pragma unroll
  for (int q = 0; q < 8; ++q) { loc[q] = s; s += cnt[base + q]; }
  part[t] = s;
  __syncthreads();
  for (int o = 1; o < 1024; o <<= 1) {
    int v = 0;
    if (t >= o) v = part[t - o];
    __syncthreads();
    part[t] += v;
    __syncthreads();
  }
  int excl = (t == 0) ? 0 : part[t - 1];
#pragma unroll
  for (int q = 0; q < 8; ++q) {
    int val = excl + loc[q];
    rs[base + q] = val;
    cur[base + q] = val;
    dis[base + q] = 1.0f / sqrtf(deg[base + q] + 1e-8f);
  }
  if (t == 1023) rs[NN] = excl + s;
}

__global__ void k_fill(const int* __restrict__ eidx, const float* __restrict__ ew,
                       int* __restrict__ cur, int* __restrict__ ccol, float* __restrict__ cw) {
  int t = blockIdx.x * blockDim.x + threadIdx.x;
  if (t >= NEDGE) return;
  int i = t / TOPK;
  int j = eidx[t] & (NN - 1);
  float h = 0.5f * ew[t];
  int s1 = atomicAdd(&cur[i], 1); ccol[s1] = j; cw[s1] = h;
  int s2 = atomicAdd(&cur[j], 1); ccol[s2] = i; cw[s2] = h;
}

// ====================================================================================
// B-stationary barrier-free MFMA GEMMs.
// Reassociation: (A_norm@h)@Wm^T == A_norm@(h@Wm^T), so the two dense GEMMs after h
// share A=h (dual output hm,hs), and bias+relu+add move into the SpMV epilogue.
// Each block: stage its 64-col W panel (64x512 bf16) into LDS ONCE (one barrier),
// then stream A rows from global straight into MFMA A-fragments -- ZERO barriers in
// the K loop. Waves progress independently; loads pipeline under MFMA automatically.
// BPAD=516 u16 -> row stride 258 dwords == 2 mod 32 (same conflict class as old LPAD).
// ====================================================================================

// ---- GEMM1: h = relu(gene@Wg^T + b) + relu(coords-MLP).  512 thr, BM=256, grid (32,8) ----
__global__ __launch_bounds__(512, 2) void k_bgemm0(const void* __restrict__ Araw,
                                                   const u16* __restrict__ Aconv,
                                                   const u16* __restrict__ W,
                                                   const float* __restrict__ bias,
                                                   const float* __restrict__ coords,
                                                   const float* __restrict__ Wc1,
                                                   const float* __restrict__ bc1,
                                                   const int* __restrict__ flag,
                                                   u16* __restrict__ outp) {
  __shared__ u16 Bs[64][BPAD];
  const int tid = threadIdx.x, lane = tid & 63, w = tid >> 6;
  const int quad = lane >> 4, l16 = lane & 15;
  const int row0 = blockIdx.x * 256, col0 = blockIdx.y * 64;
  int flg = *flag;
  const u16* A = flg ? (const u16*)Araw : Aconv;

  // stage B panel: 64 rows x 64 chunks of 8 u16
#pragma unroll
  for (int q = 0; q < 8; ++q) {
    int idx = tid + 512 * q;
    int r = idx >> 6, c = idx & 63;
    *(uint4*)(&Bs[r][c * 8]) = *(const uint4*)(W + (size_t)(col0 + r) * 512 + c * 8);
  }
  __syncthreads();

  f32x4 acc[2][4];
#pragma unroll
  for (int mr = 0; mr < 2; ++mr)
#pragma unroll
    for (int n = 0; n < 4; ++n) acc[mr][n] = (f32x4){0.f, 0.f, 0.f, 0.f};

  const u16* Ab = A + (size_t)(row0 + w * 32 + l16) * 512 + quad * 8;
#pragma unroll
  for (int kc = 0; kc < 16; ++kc) {
    bf16x8 af0 = *(const bf16x8*)(Ab + kc * 32);
    bf16x8 af1 = *(const bf16x8*)(Ab + 16 * 512 + kc * 32);
    bf16x8 bfr[4];
#pragma unroll
    for (int n = 0; n < 4; ++n)
      bfr[n] = *(const bf16x8*)(&Bs[n * 16 + l16][kc * 32 + quad * 8]);
#pragma unroll
    for (int n = 0; n < 4; ++n) {
      acc[0][n] = __builtin_amdgcn_mfma_f32_16x16x32_bf16(af0, bfr[n], acc[0][n], 0, 0, 0);
      acc[1][n] = __builtin_amdgcn_mfma_f32_16x16x32_bf16(af1, bfr[n], acc[1][n], 0, 0, 0);
    }
  }

  __syncthreads();                 // all waves done reading Bs -> reuse as staging tile
  u16* St = &Bs[0][0];             // [256][64]
#pragma unroll
  for (int mr = 0; mr < 2; ++mr) {
    int rloc = w * 32 + mr * 16 + quad * 4;
    int rbase = row0 + rloc;
    float cx[4], cy[4];
#pragma unroll
    for (int reg = 0; reg < 4; ++reg) { cx[reg] = coords[2 * (rbase + reg)]; cy[reg] = coords[2 * (rbase + reg) + 1]; }
#pragma unroll
    for (int n = 0; n < 4; ++n) {
      int cg = col0 + n * 16 + l16;
      float bval = bias[cg];
      float wc0 = Wc1[2 * cg], wc1 = Wc1[2 * cg + 1], bcv = bc1[cg];
#pragma unroll
      for (int reg = 0; reg < 4; ++reg) {
        float v = acc[mr][n][reg] + bval;
        float hc = cx[reg] * wc0 + cy[reg] * wc1 + bcv;
        v = fmaxf(v, 0.f) + fmaxf(hc, 0.f);
        St[(rloc + reg) * 64 + n * 16 + l16] = f2bf(v);
      }
    }
  }
  __syncthreads();
#pragma unroll
  for (int q = 0; q < 4; ++q) {
    int idx = tid + 512 * q;
    int r = idx >> 3, c = idx & 7;
    *(uint4*)(outp + (size_t)(row0 + r) * 512 + col0 + c * 8) = ((const uint4*)St)[idx];
  }
}

// ---- dual GEMM: hm = h@Wm^T (raw), hs = relu(h@Ws^T + b_self). Wcat = [Wm;Ws] 1024 rows ----
__global__ __launch_bounds__(512, 4) void k_bgemm_dual(const u16* __restrict__ A,
                                                       const u16* __restrict__ Wcat,
                                                       const float* __restrict__ bself,
                                                       u16* __restrict__ hm,
                                                       u16* __restrict__ hs) {
  __shared__ u16 Bs[64][BPAD];
  const int tid = threadIdx.x, lane = tid & 63, w = tid >> 6;
  const int quad = lane >> 4, l16 = lane & 15;
  const int row0 = blockIdx.x * 256, col0 = blockIdx.y * 64;   // col0 in [0,1024)
  const int selfhalf = (col0 >= 512);

#pragma unroll
  for (int q = 0; q < 8; ++q) {
    int idx = tid + 512 * q;
    int r = idx >> 6, c = idx & 63;
    *(uint4*)(&Bs[r][c * 8]) = *(const uint4*)(Wcat + (size_t)(col0 + r) * 512 + c * 8);
  }
  __syncthreads();

  f32x4 acc[2][4];
#pragma unroll
  for (int mr = 0; mr < 2; ++mr)
#pragma unroll
    for (int n = 0; n < 4; ++n) acc[mr][n] = (f32x4){0.f, 0.f, 0.f, 0.f};

  const u16* Ab = A + (size_t)(row0 + w * 32 + l16) * 512 + quad * 8;
#pragma unroll
  for (int kc = 0; kc < 16; ++kc) {
    bf16x8 af0 = *(const bf16x8*)(Ab + kc * 32);
    bf16x8 af1 = *(const bf16x8*)(Ab + 16 * 512 + kc * 32);
    bf16x8 bfr[4];
#pragma unroll
    for (int n = 0; n < 4; ++n)
      bfr[n] = *(const bf16x8*)(&Bs[n * 16 + l16][kc * 32 + quad * 8]);
#pragma unroll
    for (int n = 0; n < 4; ++n) {
      acc[0][n] = __builtin_amdgcn_mfma_f32_16x16x32_bf16(af0, bfr[n], acc[0][n], 0, 0, 0);
      acc[1][n] = __builtin_amdgcn_mfma_f32_16x16x32_bf16(af1, bfr[n], acc[1][n], 0, 0, 0);
    }
  }

  __syncthreads();
  u16* St = &Bs[0][0];             // [256][64]
  const int dcol0 = col0 & 511;
#pragma unroll
  for (int mr = 0; mr < 2; ++mr) {
    int rloc = w * 32 + mr * 16 + quad * 4;
#pragma unroll
    for (int n = 0; n < 4; ++n) {
      int cl = dcol0 + n * 16 + l16;
      float bval = selfhalf ? bself[cl] : 0.f;
#pragma unroll
      for (int reg = 0; reg < 4; ++reg) {
        float v = acc[mr][n][reg];
        if (selfhalf) v = fmaxf(v + bval, 0.f);   // hs = relu(h@Ws^T + b_self)
        St[(rloc + reg) * 64 + n * 16 + l16] = f2bf(v);  // hm raw: bias added post-agg
      }
    }
  }
  __syncthreads();
  u16* dst = selfhalf ? hs : hm;
#pragma unroll
  for (int q = 0; q < 4; ++q) {
    int idx = tid + 512 * q;
    int r = idx >> 3, c = idx & 7;
    *(uint4*)(dst + (size_t)(row0 + r) * 512 + dcol0 + c * 8) = ((const uint4*)St)[idx];
  }
}

// ---- h_final = relu(relu(A_norm@hm + b_msg) + hs)  (SpMV + fused epilogue) ----
__global__ __launch_bounds__(256) void k_agg2(const int* __restrict__ rs, const int* __restrict__ ccol,
                                              const float* __restrict__ cw, const float* __restrict__ dis,
                                              const u16* __restrict__ hm, const u16* __restrict__ hs,
                                              const float* __restrict__ bmsg, u16* __restrict__ hf) {
  int i = blockIdx.x, t = threadIdx.x;
  int b = rs[i], e = rs[i + 1];
  float di = dis[i];
  float s0 = 0.f, s1 = 0.f;
  for (int q = b; q < e; ++q) {
    int c = ccol[q];
    float w = cw[q] * dis[c];
    u32 p = *(const u32*)(hm + (size_t)c * HH + 2 * t);
    s0 = fmaf(w, bf2f((u16)(p & 0xffff)), s0);
    s1 = fmaf(w, bf2f((u16)(p >> 16)), s1);
  }
  float m0 = fmaxf(fmaf(di, s0, bmsg[2 * t]), 0.f);
  float m1 = fmaxf(fmaf(di, s1, bmsg[2 * t + 1]), 0.f);
  u32 sp = *(const u32*)(hs + (size_t)i * HH + 2 * t);
  float f0 = fmaxf(m0 + bf2f((u16)(sp & 0xffff)), 0.f);
  float f1 = fmaxf(m1 + bf2f((u16)(sp >> 16)), 0.f);
  u32 packed = (u32)f2bf(f0) | ((u32)f2bf(f1) << 16);
  *(u32*)(hf + (size_t)i * HH + 2 * t) = packed;
}

// ---- GEMM3: out = h_final@Wz^T + bz.  128 thr (2 waves), BM=32, grid 256 ----
__global__ __launch_bounds__(128) void k_bgemm3(const u16* __restrict__ A,
                                                const u16* __restrict__ W,
                                                const float* __restrict__ bias,
                                                const int* __restrict__ flag,
                                                void* __restrict__ outp) {
  __shared__ u16 Bs[64][BPAD];
  const int tid = threadIdx.x, lane = tid & 63, w = tid >> 6;   // w in {0,1}
  const int quad = lane >> 4, l16 = lane & 15;
  const int row0 = blockIdx.x * 32;
  int flg = *flag;

#pragma unroll
  for (int q = 0; q < 32; ++q) {
    int idx = tid + 128 * q;
    int r = idx >> 6, c = idx & 63;
    *(uint4*)(&Bs[r][c * 8]) = *(const uint4*)(W + (size_t)r * 512 + c * 8);
  }
  __syncthreads();

  f32x4 acc[4];
#pragma unroll
  for (int n = 0; n < 4; ++n) acc[n] = (f32x4){0.f, 0.f, 0.f, 0.f};

  const u16* Ab = A + (size_t)(row0 + w * 16 + l16) * 512 + quad * 8;
#pragma unroll
  for (int kc = 0; kc < 16; ++kc) {
    bf16x8 af = *(const bf16x8*)(Ab + kc * 32);
    bf16x8 bfr[4];
#pragma unroll
    for (int n = 0; n < 4; ++n)
      bfr[n] = *(const bf16x8*)(&Bs[n * 16 + l16][kc * 32 + quad * 8]);
#pragma unroll
    for (int n = 0; n < 4; ++n)
      acc[n] = __builtin_amdgcn_mfma_f32_16x16x32_bf16(af, bfr[n], acc[n], 0, 0, 0);
  }

  if (!flg) {
    // fp32-output world: scalar dword stores (full sectors)
#pragma unroll
    for (int n = 0; n < 4; ++n) {
      int cg = n * 16 + l16;
      float bval = bias[cg];
#pragma unroll
      for (int reg = 0; reg < 4; ++reg) {
        int rg = row0 + w * 16 + quad * 4 + reg;
        ((float*)outp)[(size_t)rg * 64 + cg] = acc[n][reg] + bval;
      }
    }
    return;
  }

  __syncthreads();
  u16* St = &Bs[0][0];             // [32][64]
#pragma unroll
  for (int n = 0; n < 4; ++n) {
    int cg = n * 16 + l16;
    float bval = bias[cg];
#pragma unroll
    for (int reg = 0; reg < 4; ++reg) {
      int rloc = w * 16 + quad * 4 + reg;
      St[rloc * 64 + cg] = f2bf(acc[n][reg] + bval);
    }
  }
  __syncthreads();
#pragma unroll
  for (int q = 0; q < 2; ++q) {
    int idx = tid + 128 * q;
    int r = idx >> 3, c = idx & 7;
    *(uint4*)((u16*)outp + (size_t)(row0 + r) * 64 + c * 8) = ((const uint4*)St)[idx];
  }
}

extern "C" void kernel_launch(void* const* d_in, const int* in_sizes, int n_in,
                              void* d_out, int out_size, void* d_ws, size_t ws_size,
                              hipStream_t stream) {
  float* ws = (float*)d_ws;
  size_t off = 0;
  auto alloc = [&](size_t n) { size_t o = off; off += (n + 15) & ~(size_t)15; return o; };

  const size_t PLANE = (size_t)NN * HH / 2;

  size_t o_flag  = alloc(16);
  size_t o_f32   = alloc(19520);
  size_t o_bfw   = alloc(409600);
  size_t o_geneB = alloc(PLANE);
  size_t o_Hb    = alloc(PLANE);
  size_t o_Mb    = alloc(PLANE);
  size_t o_sq    = alloc(NN);
  size_t o_deg   = alloc(NN);
  size_t o_dis   = alloc(NN);
  size_t o_cnt   = alloc(NN);
  size_t o_rs    = alloc(NN + 16);
  size_t o_cur   = alloc(NN);
  size_t o_eidx  = alloc(NEDGE);
  size_t o_ew    = alloc(NEDGE);
  size_t o_ccol  = alloc(NNZ);
  size_t o_cw    = alloc(NNZ);
  size_t o_pts   = alloc(NN * 4);
  size_t o_gsta  = alloc(NCELL + 16);
  size_t o_gcur  = alloc(NCELL);
  (void)ws_size;

  int*   flag    = (int*)(ws + o_flag);
  float* f32blk  = ws + o_f32;
  float* coordsF = f32blk + 0;
  float* bg1     = f32blk + 16384;
  float* Wc1f    = f32blk + 16896;
  float* bc1f    = f32blk + 17920;
  float* bmsg    = f32blk + 18432;
  float* bself   = f32blk + 18944;
  float* bz      = f32blk + 19456;
  u16*   bfblk   = (u16*)(ws + o_bfw);
  u16*   WgB     = bfblk + 0;
  u16*   WmB     = bfblk + 262144;   // [Wm;Ws] contiguous 1024x512 starting here
  u16*   WzB     = bfblk + 786432;
  u16*   geneB   = (u16*)(ws + o_geneB);
  u16*   Hb      = (u16*)(ws + o_Hb);
  u16*   Mb      = (u16*)(ws + o_Mb);
  float* sq      = ws + o_sq;
  float* deg     = ws + o_deg;
  float* dis     = ws + o_dis;
  int*   cnt     = (int*)(ws + o_cnt);
  int*   rs      = (int*)(ws + o_rs);
  int*   cur     = (int*)(ws + o_cur);
  int*   eidx    = (int*)(ws + o_eidx);
  float* ew      = ws + o_ew;
  int*   ccol    = (int*)(ws + o_ccol);
  float* cw      = ws + o_cw;
  float4* pts    = (float4*)(ws + o_pts);
  int*   gstart  = (int*)(ws + o_gsta);
  int*   gcur    = (int*)(ws + o_gcur);

  // plane reuse: hm <- geneB plane (gene no longer needed after GEMM1);
  // hs <- Mb plane; h_final <- Hb plane (h no longer needed after dual GEMM).
  u16* HM = geneB;
  u16* HS = Mb;
  u16* HF = Hb;

  InPtrs ip;
  for (int s = 0; s < 12; ++s) ip.p[s] = d_in[s];

  k_conv_small<<<512, 256, 0, stream>>>(ip, flag, f32blk, bfblk, deg, cnt, sq);
  k_conv_gene<<<2048, 256, 0, stream>>>(d_in[0], d_in[1], (u32*)geneB);
  k_grid_scan<<<1, 1024, 0, stream>>>(coordsF, gstart, gcur);
  k_grid_fill<<<NN / 256, 256, 0, stream>>>(coordsF, sq, gcur, pts);
  k_knn_grid<<<NN / 4, 256, 0, stream>>>(pts, gstart, coordsF, sq, eidx, ew);
  k_degcnt<<<(NEDGE + 255) / 256, 256, 0, stream>>>(eidx, ew, deg, cnt);
  k_scan<<<1, 1024, 0, stream>>>(cnt, deg, rs, cur, dis);
  k_fill<<<(NEDGE + 255) / 256, 256, 0, stream>>>(eidx, ew, cur, ccol, cw);

  k_bgemm0<<<dim3(32, 8), 512, 0, stream>>>(d_in[0], geneB, WgB, bg1, coordsF, Wc1f, bc1f, flag, Hb);
  k_bgemm_dual<<<dim3(32, 16), 512, 0, stream>>>(Hb, WmB, bself, HM, HS);
  k_agg2<<<NN, 256, 0, stream>>>(rs, ccol, cw, dis, HM, HS, bmsg, HF);
  k_bgemm3<<<256, 128, 0, stream>>>(HF, WzB, bz, flag, d_out);
}

// Round 3
// 232.567 us; speedup vs baseline: 1.3489x; 1.0007x over previous
//
#include <hip/hip_runtime.h>
#include <hip/hip_bf16.h>
#include <stdint.h>

#define NN 8192
#define GG 512
#define HH 512
#define LL 64
#define TOPK 9                 // K+1 = 9 (incl. self, self weight zeroed)
#define NEDGE (NN*TOPK)        // 73728 directed edges
#define NNZ (2*NEDGE)          // 147456 CSR entries after symmetrization
#define GRES 32                // spatial grid resolution (cell = 1/32)
#define NCELL (GRES*GRES)
#define BPAD 516               // LDS B-panel row pad: 258 dwords == 2 mod 32 (conflict-free class)

typedef unsigned long long u64;
typedef unsigned int u32;
typedef unsigned short u16;

using bf16x8 = __attribute__((ext_vector_type(8))) short;
using f32x4  = __attribute__((ext_vector_type(4))) float;

struct InPtrs { const void* p[12]; };

__device__ __forceinline__ float bf2f(u16 u) { return __uint_as_float(((u32)u) << 16); }
__device__ __forceinline__ u16 f2bf(float f) {
  u32 x = __float_as_uint(f);
  u32 r = x + 0x7fffu + ((x >> 16) & 1u);   // RNE
  return (u16)(r >> 16);
}

// ---------------- inline dtype detection (wave 0 samples 64 u16s of coords) ----------------
__device__ __forceinline__ int detect_isbf(const void* coords_raw, int tid, int* sh) {
  if (tid < 64) {
    float v = bf2f(((const u16*)coords_raw)[tid]);
    bool bad = !(v >= -0.01f && v <= 1.02f);
    u64 bb = __ballot(bad);
    if (tid == 0) *sh = (bb == 0ULL) ? 1 : 0;
  }
  __syncthreads();
  return *sh;
}

// ---------------- convert small tensors + flag + zero deg/cnt + sq (from raw coords) ----------------
__global__ void k_conv_small(InPtrs in, int* __restrict__ flag,
                             float* __restrict__ f32blk, u16* __restrict__ bfblk,
                             float* __restrict__ deg, int* __restrict__ cnt,
                             float* __restrict__ sq) {
  __shared__ int sh;
  const int cnts[11] = {16384, 262144, 512, 1024, 512, 262144, 512, 262144, 512, 32768, 64};
  const int kind[11] = {0, 1, 0, 0, 0, 1, 0, 1, 0, 1, 0};
  const int doff[11] = {0, 0, 16384, 16896, 17920, 262144, 18432, 524288, 18944, 786432, 19456};
  const int TOTAL = 838720;
  int tid = threadIdx.x;
  int isbf = detect_isbf(in.p[1], tid, &sh);
  int gtid = blockIdx.x * blockDim.x + tid;
  if (gtid == 0) *flag = isbf;
  if (gtid < NN) {
    deg[gtid] = 0.0f;
    float x, y;
    if (isbf) { x = bf2f(((const u16*)in.p[1])[2 * gtid]); y = bf2f(((const u16*)in.p[1])[2 * gtid + 1]); }
    else      { x = ((const float*)in.p[1])[2 * gtid];     y = ((const float*)in.p[1])[2 * gtid + 1]; }
    sq[gtid] = __fadd_rn(__fmul_rn(x, x), __fmul_rn(y, y));
  } else if (gtid < 2 * NN) {
    cnt[gtid - NN] = 0;
  }
  for (int e = gtid; e < TOTAL; e += gridDim.x * blockDim.x) {
    int base = 0;
#pragma unroll
    for (int s = 0; s < 11; ++s) {
      if (e < base + cnts[s]) {
        int loc = e - base;
        const void* src = in.p[s + 1];
        float fv = isbf ? bf2f(((const u16*)src)[loc]) : ((const float*)src)[loc];
        if (kind[s] == 0) f32blk[doff[s] + loc] = fv;
        else bfblk[doff[s] + loc] = isbf ? ((const u16*)src)[loc] : f2bf(fv);
        break;
      }
      base += cnts[s];
    }
  }
}

// ---------------- gene -> bf16 ONLY in the fp32-input world ----------------
__global__ void k_conv_gene(const void* __restrict__ src, const void* __restrict__ coords_raw,
                            u32* __restrict__ geneB) {
  __shared__ int sh;
  const int TOTAL = NN * GG / 2;
  int isbf = detect_isbf(coords_raw, threadIdx.x, &sh);
  if (isbf) return;
  for (int e = blockIdx.x * blockDim.x + threadIdx.x; e < TOTAL; e += gridDim.x * blockDim.x) {
    float2 f = ((const float2*)src)[e];
    geneB[e] = (u32)f2bf(f.x) | ((u32)f2bf(f.y) << 16);
  }
}

__device__ __forceinline__ int cell_of(float v) {
  int c = (int)(v * (float)GRES);
  return c < 0 ? 0 : (c > GRES - 1 ? GRES - 1 : c);
}

// ---------------- grid histogram + scan + fill (single block; LDS cursor) ----------------
__global__ __launch_bounds__(1024) void k_grid(const float* __restrict__ coords,
                                               const float* __restrict__ sq,
                                               int* __restrict__ gstart,
                                               float4* __restrict__ pts) {
  __shared__ int hist[NCELL];
  __shared__ int part[NCELL];
  int t = threadIdx.x;
  hist[t] = 0;
  __syncthreads();
#pragma unroll
  for (int q = 0; q < 8; ++q) {
    int i = t + 1024 * q;
    int cx = cell_of(coords[2 * i]), cy = cell_of(coords[2 * i + 1]);
    atomicAdd(&hist[cy * GRES + cx], 1);
  }
  __syncthreads();
  int v = hist[t];
  part[t] = v;
  __syncthreads();
  for (int o = 1; o < NCELL; o <<= 1) {
    int add = 0;
    if (t >= o) add = part[t - o];
    __syncthreads();
    part[t] += add;
    __syncthreads();
  }
  int excl = part[t] - v;
  gstart[t] = excl;
  hist[t] = excl;                 // reuse hist as the fill cursor (LDS atomics)
  if (t == NCELL - 1) gstart[NCELL] = part[t];
  __syncthreads();
#pragma unroll
  for (int q = 0; q < 8; ++q) {
    int i = t + 1024 * q;
    float x = coords[2 * i], y = coords[2 * i + 1];
    int cx = cell_of(x), cy = cell_of(y);
    int p = atomicAdd(&hist[cy * GRES + cx], 1);
    pts[p] = make_float4(x, y, sq[i], __int_as_float(i));
  }
}

// ---------------- KNN top-9 via spatial grid (exact; inline full-scan fallback) ----------------
__global__ __launch_bounds__(256) void k_knn_grid(const float4* __restrict__ pts,
                                                  const int* __restrict__ gstart,
                                                  const float* __restrict__ coords,
                                                  const float* __restrict__ sq,
                                                  int* __restrict__ eidx, float* __restrict__ ew) {
  const int w = threadIdx.x >> 6, lane = threadIdx.x & 63;
  const int i = blockIdx.x * 4 + w;
  const float qx = coords[2*i], qy = coords[2*i+1];
  const float sqi = sq[i];
  const int cx = cell_of(qx), cy = cell_of(qy);
  const int x0 = max(cx - 2, 0), x1 = min(cx + 2, GRES - 1);
  const int y0 = max(cy - 2, 0), y1 = min(cy + 2, GRES - 1);

  u64 a0 = ~0ULL, a1 = ~0ULL, a2 = ~0ULL, a3 = ~0ULL, a4 = ~0ULL,
      a5 = ~0ULL, a6 = ~0ULL, a7 = ~0ULL, a8 = ~0ULL;

#define KSTEP(A) { u64 t_ = A; bool p_ = x < t_; A = p_ ? x : t_; x = p_ ? t_ : x; }
  for (int yy = y0; yy <= y1; ++yy) {
    int sbeg = gstart[yy * GRES + x0];
    int send = gstart[yy * GRES + x1 + 1];
    for (int p = sbeg + lane; p < send; p += 64) {
      float4 pt = pts[p];
      float dot = __fmaf_rn(qy, pt.y, __fmul_rn(qx, pt.x));
      float d2  = __fsub_rn(__fadd_rn(sqi, pt.z), __fmul_rn(2.0f, dot));
      float d   = __fsqrt_rn(fmaxf(d2, 0.0f));
      u64 x = ((u64)__float_as_uint(d) << 32) | (u32)__float_as_int(pt.w);
      KSTEP(a0) KSTEP(a1) KSTEP(a2) KSTEP(a3) KSTEP(a4)
      KSTEP(a5) KSTEP(a6) KSTEP(a7) KSTEP(a8)
    }
  }

  u64 g9 = ~0ULL;
  for (int r = 0; r < TOPK; ++r) {
    u64 g = a0;
#pragma unroll
    for (int o = 32; o > 0; o >>= 1) {
      u64 other = __shfl_xor(g, o, 64);
      if (other < g) g = other;
    }
    bool own = (a0 == g);
    a0 = own ? a1 : a0;  a1 = own ? a2 : a1;  a2 = own ? a3 : a2;
    a3 = own ? a4 : a3;  a4 = own ? a5 : a4;  a5 = own ? a6 : a5;
    a6 = own ? a7 : a6;  a7 = own ? a8 : a7;  a8 = own ? ~0ULL : a8;
    g9 = g;
    if (lane == 0) {
      u32 dbits = (u32)(g >> 32);
      int j = (int)(g & 0xffffffffu);
      float d = __uint_as_float(dbits);
      float wgt = (j == i) ? 0.0f : expf(__fdiv_rn(-__fmul_rn(d, d), 2.0f));
      eidx[i * TOPK + r] = j;
      ew[i * TOPK + r] = wgt;
    }
  }

  float d9 = __uint_as_float((u32)(g9 >> 32));
  if (!(d9 < 0.0624f)) {
    a0 = a1 = a2 = a3 = a4 = a5 = a6 = a7 = a8 = ~0ULL;
    const float2* c2 = (const float2*)coords;
    for (int c = 0; c < 128; ++c) {
      int j = c * 64 + lane;
      float2 cjf = c2[j];
      float dot = __fmaf_rn(qy, cjf.y, __fmul_rn(qx, cjf.x));
      float d2  = __fsub_rn(__fadd_rn(sqi, sq[j]), __fmul_rn(2.0f, dot));
      float d   = __fsqrt_rn(fmaxf(d2, 0.0f));
      u64 x = ((u64)__float_as_uint(d) << 32) | (u32)j;
      KSTEP(a0) KSTEP(a1) KSTEP(a2) KSTEP(a3) KSTEP(a4)
      KSTEP(a5) KSTEP(a6) KSTEP(a7) KSTEP(a8)
    }
    for (int r = 0; r < TOPK; ++r) {
      u64 g = a0;
#pragma unroll
      for (int o = 32; o > 0; o >>= 1) {
        u64 other = __shfl_xor(g, o, 64);
        if (other < g) g = other;
      }
      bool own = (a0 == g);
      a0 = own ? a1 : a0;  a1 = own ? a2 : a1;  a2 = own ? a3 : a2;
      a3 = own ? a4 : a3;  a4 = own ? a5 : a4;  a5 = own ? a6 : a5;
      a6 = own ? a7 : a6;  a7 = own ? a8 : a7;  a8 = own ? ~0ULL : a8;
      if (lane == 0) {
        u32 dbits = (u32)(g >> 32);
        int j = (int)(g & 0xffffffffu);
        float d = __uint_as_float(dbits);
        float wgt = (j == i) ? 0.0f : expf(__fdiv_rn(-__fmul_rn(d, d), 2.0f));
        eidx[i * TOPK + r] = j;
        ew[i * TOPK + r] = wgt;
      }
    }
  }
#undef KSTEP
}

// ---------------- fused degree + count ----------------
__global__ void k_degcnt(const int* __restrict__ eidx, const float* __restrict__ ew,
                         float* __restrict__ deg, int* __restrict__ cnt) {
  int t = blockIdx.x * blockDim.x + threadIdx.x;
  if (t >= NEDGE) return;
  int i = t / TOPK;
  int j = eidx[t] & (NN - 1);
  float h = 0.5f * ew[t];
  atomicAdd(&deg[i], h);
  atomicAdd(&deg[j], h);
  atomicAdd(&cnt[i], 1);
  atomicAdd(&cnt[j], 1);
}

// ---------------- CSR scan (+ dis from deg) ----------------
__global__ __launch_bounds__(1024) void k_scan(const int* __restrict__ cnt,
                                               const float* __restrict__ deg,
                                               int* __restrict__ rs, int* __restrict__ cur,
                                               float* __restrict__ dis) {
  __shared__ int part[1024];
  int t = threadIdx.x;
  int base = t * 8;
  int loc[8]; int s = 0;
#pragma unroll
  for (int q = 0; q < 8; ++q) { loc[q] = s; s += cnt[base + q]; }
  part[t] = s;
  __syncthreads();
  for (int o = 1; o < 1024; o <<= 1) {
    int v = 0;
    if (t >= o) v = part[t - o];
    __syncthreads();
    part[t] += v;
    __syncthreads();
  }
  int excl = (t == 0) ? 0 : part[t - 1];
#pragma unroll
  for (int q = 0; q < 8; ++q) {
    int val = excl + loc[q];
    rs[base + q] = val;
    cur[base + q] = val;
    dis[base + q] = 1.0f / sqrtf(deg[base + q] + 1e-8f);
  }
  if (t == 1023) rs[NN] = excl + s;
}

__global__ void k_fill(const int* __restrict__ eidx, const float* __restrict__ ew,
                       int* __restrict__ cur, int* __restrict__ ccol, float* __restrict__ cw) {
  int t = blockIdx.x * blockDim.x + threadIdx.x;
  if (t >= NEDGE) return;
  int i = t / TOPK;
  int j = eidx[t] & (NN - 1);
  float h = 0.5f * ew[t];
  int s1 = atomicAdd(&cur[i], 1); ccol[s1] = j; cw[s1] = h;
  int s2 = atomicAdd(&cur[j], 1); ccol[s2] = i; cw[s2] = h;
}

// ====================================================================================
// B-stationary barrier-free MFMA GEMMs (see round-2 notes).
// ====================================================================================

// ---- GEMM1: h = relu(gene@Wg^T + b) + relu(coords-MLP).  512 thr, BM=128, grid (64,8) ----
// 2 blocks/CU (LDS 66KB x2), 16 waves/CU -- double the old (32,8) config's occupancy.
__global__ __launch_bounds__(512, 4) void k_bgemm0(const void* __restrict__ Araw,
                                                   const u16* __restrict__ Aconv,
                                                   const u16* __restrict__ W,
                                                   const float* __restrict__ bias,
                                                   const float* __restrict__ coords,
                                                   const float* __restrict__ Wc1,
                                                   const float* __restrict__ bc1,
                                                   const int* __restrict__ flag,
                                                   u16* __restrict__ outp) {
  __shared__ u16 Bs[64][BPAD];
  const int tid = threadIdx.x, lane = tid & 63, w = tid >> 6;
  const int quad = lane >> 4, l16 = lane & 15;
  const int row0 = blockIdx.x * 128, col0 = blockIdx.y * 64;
  int flg = *flag;
  const u16* A = flg ? (const u16*)Araw : Aconv;

  // stage B panel: 64 rows x 64 chunks of 8 u16
#pragma unroll
  for (int q = 0; q < 8; ++q) {
    int idx = tid + 512 * q;
    int r = idx >> 6, c = idx & 63;
    *(uint4*)(&Bs[r][c * 8]) = *(const uint4*)(W + (size_t)(col0 + r) * 512 + c * 8);
  }
  __syncthreads();

  f32x4 acc[4];
#pragma unroll
  for (int n = 0; n < 4; ++n) acc[n] = (f32x4){0.f, 0.f, 0.f, 0.f};

  const u16* Ab = A + (size_t)(row0 + w * 16 + l16) * 512 + quad * 8;
#pragma unroll
  for (int kc = 0; kc < 16; ++kc) {
    bf16x8 af = *(const bf16x8*)(Ab + kc * 32);
    bf16x8 bfr[4];
#pragma unroll
    for (int n = 0; n < 4; ++n)
      bfr[n] = *(const bf16x8*)(&Bs[n * 16 + l16][kc * 32 + quad * 8]);
#pragma unroll
    for (int n = 0; n < 4; ++n)
      acc[n] = __builtin_amdgcn_mfma_f32_16x16x32_bf16(af, bfr[n], acc[n], 0, 0, 0);
  }

  __syncthreads();                 // all waves done reading Bs -> reuse as staging tile
  u16* St = &Bs[0][0];             // [128][64]
  {
    int rloc = w * 16 + quad * 4;
    int rbase = row0 + rloc;
    float cx[4], cy[4];
#pragma unroll
    for (int reg = 0; reg < 4; ++reg) { cx[reg] = coords[2 * (rbase + reg)]; cy[reg] = coords[2 * (rbase + reg) + 1]; }
#pragma unroll
    for (int n = 0; n < 4; ++n) {
      int cg = col0 + n * 16 + l16;
      float bval = bias[cg];
      float wc0 = Wc1[2 * cg], wc1 = Wc1[2 * cg + 1], bcv = bc1[cg];
#pragma unroll
      for (int reg = 0; reg < 4; ++reg) {
        float v = acc[n][reg] + bval;
        float hc = cx[reg] * wc0 + cy[reg] * wc1 + bcv;
        v = fmaxf(v, 0.f) + fmaxf(hc, 0.f);
        St[(rloc + reg) * 64 + n * 16 + l16] = f2bf(v);
      }
    }
  }
  __syncthreads();
#pragma unroll
  for (int q = 0; q < 2; ++q) {
    int idx = tid + 512 * q;
    int r = idx >> 3, c = idx & 7;
    *(uint4*)(outp + (size_t)(row0 + r) * 512 + col0 + c * 8) = ((const uint4*)St)[idx];
  }
}

// ---- dual GEMM: hm = h@Wm^T (raw), hs = relu(h@Ws^T + b_self). Wcat = [Wm;Ws] 1024 rows ----
__global__ __launch_bounds__(512, 4) void k_bgemm_dual(const u16* __restrict__ A,
                                                       const u16* __restrict__ Wcat,
                                                       const float* __restrict__ bself,
                                                       u16* __restrict__ hm,
                                                       u16* __restrict__ hs) {
  __shared__ u16 Bs[64][BPAD];
  const int tid = threadIdx.x, lane = tid & 63, w = tid >> 6;
  const int quad = lane >> 4, l16 = lane & 15;
  const int row0 = blockIdx.x * 256, col0 = blockIdx.y * 64;   // col0 in [0,1024)
  const int selfhalf = (col0 >= 512);

#pragma unroll
  for (int q = 0; q < 8; ++q) {
    int idx = tid + 512 * q;
    int r = idx >> 6, c = idx & 63;
    *(uint4*)(&Bs[r][c * 8]) = *(const uint4*)(Wcat + (size_t)(col0 + r) * 512 + c * 8);
  }
  __syncthreads();

  f32x4 acc[2][4];
#pragma unroll
  for (int mr = 0; mr < 2; ++mr)
#pragma unroll
    for (int n = 0; n < 4; ++n) acc[mr][n] = (f32x4){0.f, 0.f, 0.f, 0.f};

  const u16* Ab = A + (size_t)(row0 + w * 32 + l16) * 512 + quad * 8;
#pragma unroll
  for (int kc = 0; kc < 16; ++kc) {
    bf16x8 af0 = *(const bf16x8*)(Ab + kc * 32);
    bf16x8 af1 = *(const bf16x8*)(Ab + 16 * 512 + kc * 32);
    bf16x8 bfr[4];
#pragma unroll
    for (int n = 0; n < 4; ++n)
      bfr[n] = *(const bf16x8*)(&Bs[n * 16 + l16][kc * 32 + quad * 8]);
#pragma unroll
    for (int n = 0; n < 4; ++n) {
      acc[0][n] = __builtin_amdgcn_mfma_f32_16x16x32_bf16(af0, bfr[n], acc[0][n], 0, 0, 0);
      acc[1][n] = __builtin_amdgcn_mfma_f32_16x16x32_bf16(af1, bfr[n], acc[1][n], 0, 0, 0);
    }
  }

  __syncthreads();
  u16* St = &Bs[0][0];             // [256][64]
  const int dcol0 = col0 & 511;
#pragma unroll
  for (int mr = 0; mr < 2; ++mr) {
    int rloc = w * 32 + mr * 16 + quad * 4;
#pragma unroll
    for (int n = 0; n < 4; ++n) {
      int cl = dcol0 + n * 16 + l16;
      float bval = selfhalf ? bself[cl] : 0.f;
#pragma unroll
      for (int reg = 0; reg < 4; ++reg) {
        float v = acc[mr][n][reg];
        if (selfhalf) v = fmaxf(v + bval, 0.f);   // hs = relu(h@Ws^T + b_self)
        St[(rloc + reg) * 64 + n * 16 + l16] = f2bf(v);  // hm raw: bias added post-agg
      }
    }
  }
  __syncthreads();
  u16* dst = selfhalf ? hs : hm;
#pragma unroll
  for (int q = 0; q < 4; ++q) {
    int idx = tid + 512 * q;
    int r = idx >> 3, c = idx & 7;
    *(uint4*)(dst + (size_t)(row0 + r) * 512 + dcol0 + c * 8) = ((const uint4*)St)[idx];
  }
}

// ---- h_final = relu(relu(A_norm@hm + b_msg) + hs)  (SpMV, 4-edge-wide gather) ----
// 4 groups of 64 lanes; group g handles edges b+4q+g with uint4 (16B) row loads, so
// the serial dependent-load chain shrinks ~3.6x and each load is full-width. 8 KB LDS
// cross-group reduce, then the fused bias/relu/self epilogue.
__global__ __launch_bounds__(256) void k_agg2(const int* __restrict__ rs, const int* __restrict__ ccol,
                                              const float* __restrict__ cw, const float* __restrict__ dis,
                                              const u16* __restrict__ hm, const u16* __restrict__ hs,
                                              const float* __restrict__ bmsg, u16* __restrict__ hf) {
  __shared__ float sacc[4][512];
  const int i = blockIdx.x, t = threadIdx.x;
  const int g = t >> 6, l = t & 63;
  const int b = rs[i], e = rs[i + 1];
  float acc[8];
#pragma unroll
  for (int j = 0; j < 8; ++j) acc[j] = 0.f;
  for (int q = b + g; q < e; q += 4) {
    int c = ccol[q];
    float w = cw[q] * dis[c];
    uint4 p = *(const uint4*)(hm + (size_t)c * HH + l * 8);
    acc[0] = fmaf(w, bf2f((u16)(p.x & 0xffff)), acc[0]);
    acc[1] = fmaf(w, bf2f((u16)(p.x >> 16)),    acc[1]);
    acc[2] = fmaf(w, bf2f((u16)(p.y & 0xffff)), acc[2]);
    acc[3] = fmaf(w, bf2f((u16)(p.y >> 16)),    acc[3]);
    acc[4] = fmaf(w, bf2f((u16)(p.z & 0xffff)), acc[4]);
    acc[5] = fmaf(w, bf2f((u16)(p.z >> 16)),    acc[5]);
    acc[6] = fmaf(w, bf2f((u16)(p.w & 0xffff)), acc[6]);
    acc[7] = fmaf(w, bf2f((u16)(p.w >> 16)),    acc[7]);
  }
#pragma unroll
  for (int j = 0; j < 8; ++j) sacc[g][l * 8 + j] = acc[j];
  __syncthreads();
  float di = dis[i];
  int c0 = 2 * t, c1 = 2 * t + 1;
  float s0 = (sacc[0][c0] + sacc[1][c0]) + (sacc[2][c0] + sacc[3][c0]);
  float s1 = (sacc[0][c1] + sacc[1][c1]) + (sacc[2][c1] + sacc[3][c1]);
  float m0 = fmaxf(fmaf(di, s0, bmsg[c0]), 0.f);
  float m1 = fmaxf(fmaf(di, s1, bmsg[c1]), 0.f);
  u32 sp = *(const u32*)(hs + (size_t)i * HH + c0);
  float f0 = fmaxf(m0 + bf2f((u16)(sp & 0xffff)), 0.f);
  float f1 = fmaxf(m1 + bf2f((u16)(sp >> 16)), 0.f);
  u32 packed = (u32)f2bf(f0) | ((u32)f2bf(f1) << 16);
  *(u32*)(hf + (size_t)i * HH + c0) = packed;
}

// ---- GEMM3: out = h_final@Wz^T + bz.  BM=16, 256 thr (waves split the 4 N-frags),
// grid 512 -> 2 blocks/CU, 8 waves/CU (was 2). LDS-staged full-line output stores. ----
__global__ __launch_bounds__(256) void k_bgemm3(const u16* __restrict__ A,
                                                const u16* __restrict__ W,
                                                const float* __restrict__ bias,
                                                const int* __restrict__ flag,
                                                void* __restrict__ outp) {
  __shared__ u16 Bs[64][BPAD];
  const int tid = threadIdx.x, lane = tid & 63, w = tid >> 6;   // w = n-frag 0..3
  const int quad = lane >> 4, l16 = lane & 15;
  const int row0 = blockIdx.x * 16;
  int flg = *flag;

#pragma unroll
  for (int q = 0; q < 16; ++q) {
    int idx = tid + 256 * q;
    int r = idx >> 6, c = idx & 63;
    *(uint4*)(&Bs[r][c * 8]) = *(const uint4*)(W + (size_t)r * 512 + c * 8);
  }
  __syncthreads();

  f32x4 acc = (f32x4){0.f, 0.f, 0.f, 0.f};
  const u16* Ab = A + (size_t)(row0 + l16) * 512 + quad * 8;
#pragma unroll
  for (int kc = 0; kc < 16; ++kc) {
    bf16x8 af  = *(const bf16x8*)(Ab + kc * 32);
    bf16x8 bfw = *(const bf16x8*)(&Bs[w * 16 + l16][kc * 32 + quad * 8]);
    acc = __builtin_amdgcn_mfma_f32_16x16x32_bf16(af, bfw, acc, 0, 0, 0);
  }

  __syncthreads();
  if (!flg) {
    // fp32-output world (LIVE path for fp32 inputs): stage [16][64] f32 tile, float4 stores
    float* Stf = (float*)&Bs[0][0];
    float bval = bias[w * 16 + l16];
#pragma unroll
    for (int reg = 0; reg < 4; ++reg)
      Stf[(quad * 4 + reg) * 64 + w * 16 + l16] = acc[reg] + bval;
    __syncthreads();
    // 16 rows x 16 float4 per row = 256 float4, one per thread
    int r = tid >> 4, c = tid & 15;
    ((float4*)outp)[(size_t)(row0 + r) * 16 + c] = ((const float4*)Stf)[tid];
    return;
  }

  u16* St = &Bs[0][0];             // [16][64] bf16
  float bval = bias[w * 16 + l16];
#pragma unroll
  for (int reg = 0; reg < 4; ++reg)
    St[(quad * 4 + reg) * 64 + w * 16 + l16] = f2bf(acc[reg] + bval);
  __syncthreads();
  if (tid < 128) {
    int r = tid >> 3, c = tid & 7;
    *(uint4*)((u16*)outp + (size_t)(row0 + r) * 64 + c * 8) = ((const uint4*)St)[tid];
  }
}

extern "C" void kernel_launch(void* const* d_in, const int* in_sizes, int n_in,
                              void* d_out, int out_size, void* d_ws, size_t ws_size,
                              hipStream_t stream) {
  float* ws = (float*)d_ws;
  size_t off = 0;
  auto alloc = [&](size_t n) { size_t o = off; off += (n + 15) & ~(size_t)15; return o; };

  const size_t PLANE = (size_t)NN * HH / 2;

  size_t o_flag  = alloc(16);
  size_t o_f32   = alloc(19520);
  size_t o_bfw   = alloc(409600);
  size_t o_geneB = alloc(PLANE);
  size_t o_Hb    = alloc(PLANE);
  size_t o_Mb    = alloc(PLANE);
  size_t o_sq    = alloc(NN);
  size_t o_deg   = alloc(NN);
  size_t o_dis   = alloc(NN);
  size_t o_cnt   = alloc(NN);
  size_t o_rs    = alloc(NN + 16);
  size_t o_cur   = alloc(NN);
  size_t o_eidx  = alloc(NEDGE);
  size_t o_ew    = alloc(NEDGE);
  size_t o_ccol  = alloc(NNZ);
  size_t o_cw    = alloc(NNZ);
  size_t o_pts   = alloc(NN * 4);
  size_t o_gsta  = alloc(NCELL + 16);
  (void)ws_size;

  int*   flag    = (int*)(ws + o_flag);
  float* f32blk  = ws + o_f32;
  float* coordsF = f32blk + 0;
  float* bg1     = f32blk + 16384;
  float* Wc1f    = f32blk + 16896;
  float* bc1f    = f32blk + 17920;
  float* bmsg    = f32blk + 18432;
  float* bself   = f32blk + 18944;
  float* bz      = f32blk + 19456;
  u16*   bfblk   = (u16*)(ws + o_bfw);
  u16*   WgB     = bfblk + 0;
  u16*   WmB     = bfblk + 262144;   // [Wm;Ws] contiguous 1024x512 starting here
  u16*   WzB     = bfblk + 786432;
  u16*   geneB   = (u16*)(ws + o_geneB);
  u16*   Hb      = (u16*)(ws + o_Hb);
  u16*   Mb      = (u16*)(ws + o_Mb);
  float* sq      = ws + o_sq;
  float* deg     = ws + o_deg;
  float* dis     = ws + o_dis;
  int*   cnt     = (int*)(ws + o_cnt);
  int*   rs      = (int*)(ws + o_rs);
  int*   cur     = (int*)(ws + o_cur);
  int*   eidx    = (int*)(ws + o_eidx);
  float* ew      = ws + o_ew;
  int*   ccol    = (int*)(ws + o_ccol);
  float* cw      = ws + o_cw;
  float4* pts    = (float4*)(ws + o_pts);
  int*   gstart  = (int*)(ws + o_gsta);

  // plane reuse: hm <- geneB plane (gene no longer needed after GEMM1);
  // hs <- Mb plane; h_final <- Hb plane (h no longer needed after dual GEMM).
  u16* HM = geneB;
  u16* HS = Mb;
  u16* HF = Hb;

  InPtrs ip;
  for (int s = 0; s < 12; ++s) ip.p[s] = d_in[s];

  k_conv_small<<<512, 256, 0, stream>>>(ip, flag, f32blk, bfblk, deg, cnt, sq);
  k_conv_gene<<<2048, 256, 0, stream>>>(d_in[0], d_in[1], (u32*)geneB);
  k_grid<<<1, 1024, 0, stream>>>(coordsF, sq, gstart, pts);
  k_knn_grid<<<NN / 4, 256, 0, stream>>>(pts, gstart, coordsF, sq, eidx, ew);
  k_degcnt<<<(NEDGE + 255) / 256, 256, 0, stream>>>(eidx, ew, deg, cnt);
  k_scan<<<1, 1024, 0, stream>>>(cnt, deg, rs, cur, dis);
  k_fill<<<(NEDGE + 255) / 256, 256, 0, stream>>>(eidx, ew, cur, ccol, cw);

  k_bgemm0<<<dim3(64, 8), 512, 0, stream>>>(d_in[0], geneB, WgB, bg1, coordsF, Wc1f, bc1f, flag, Hb);
  k_bgemm_dual<<<dim3(32, 16), 512, 0, stream>>>(Hb, WmB, bself, HM, HS);
  k_agg2<<<NN, 256, 0, stream>>>(rs, ccol, cw, dis, HM, HS, bmsg, HF);
  k_bgemm3<<<512, 256, 0, stream>>>(HF, WzB, bz, flag, d_out);
}

// Round 5
// 211.405 us; speedup vs baseline: 1.4840x; 1.1001x over previous
//
#include <hip/hip_runtime.h>
#include <hip/hip_bf16.h>
#include <stdint.h>

#define NN 8192
#define GG 512
#define HH 512
#define LL 64
#define TOPK 9                 // K+1 = 9 (incl. self, self weight zeroed)
#define NEDGE (NN*TOPK)        // 73728 directed edges
#define NNZ (2*NEDGE)          // 147456 CSR entries after symmetrization
#define GRES 32                // spatial grid resolution (cell = 1/32)
#define NCELL (GRES*GRES)
#define BPAD 516               // LDS B-panel row pad: 258 dwords == 2 mod 32 (conflict-free class)

typedef unsigned long long u64;
typedef unsigned int u32;
typedef unsigned short u16;

using bf16x8 = __attribute__((ext_vector_type(8))) short;
using f32x4  = __attribute__((ext_vector_type(4))) float;

struct InPtrs { const void* p[12]; };

__device__ __forceinline__ float bf2f(u16 u) { return __uint_as_float(((u32)u) << 16); }
__device__ __forceinline__ u16 f2bf(float f) {
  u32 x = __float_as_uint(f);
  u32 r = x + 0x7fffu + ((x >> 16) & 1u);   // RNE
  return (u16)(r >> 16);
}

// ---------------- inline dtype detection (wave 0 samples 64 u16s of coords) ----------------
__device__ __forceinline__ int detect_isbf(const void* coords_raw, int tid, int* sh) {
  if (tid < 64) {
    float v = bf2f(((const u16*)coords_raw)[tid]);
    bool bad = !(v >= -0.01f && v <= 1.02f);
    u64 bb = __ballot(bad);
    if (tid == 0) *sh = (bb == 0ULL) ? 1 : 0;
  }
  __syncthreads();
  return *sh;
}

// ---------------- convert small tensors + gene->bf16 + flag + zero deg/cnt + sq ----------------
__global__ void k_conv_small(InPtrs in, int* __restrict__ flag,
                             float* __restrict__ f32blk, u16* __restrict__ bfblk,
                             float* __restrict__ deg, int* __restrict__ cnt,
                             float* __restrict__ sq, u32* __restrict__ geneB) {
  __shared__ int sh;
  const int cnts[11] = {16384, 262144, 512, 1024, 512, 262144, 512, 262144, 512, 32768, 64};
  const int kind[11] = {0, 1, 0, 0, 0, 1, 0, 1, 0, 1, 0};
  const int doff[11] = {0, 0, 16384, 16896, 17920, 262144, 18432, 524288, 18944, 786432, 19456};
  const int TOTAL = 838720;
  int tid = threadIdx.x;
  int isbf = detect_isbf(in.p[1], tid, &sh);
  int gtid = blockIdx.x * blockDim.x + tid;
  if (gtid == 0) *flag = isbf;
  if (gtid < NN) {
    deg[gtid] = 0.0f;
    float x, y;
    if (isbf) { x = bf2f(((const u16*)in.p[1])[2 * gtid]); y = bf2f(((const u16*)in.p[1])[2 * gtid + 1]); }
    else      { x = ((const float*)in.p[1])[2 * gtid];     y = ((const float*)in.p[1])[2 * gtid + 1]; }
    sq[gtid] = __fadd_rn(__fmul_rn(x, x), __fmul_rn(y, y));
  } else if (gtid < 2 * NN) {
    cnt[gtid - NN] = 0;
  }
  for (int e = gtid; e < TOTAL; e += gridDim.x * blockDim.x) {
    int base = 0;
#pragma unroll
    for (int s = 0; s < 11; ++s) {
      if (e < base + cnts[s]) {
        int loc = e - base;
        const void* src = in.p[s + 1];
        float fv = isbf ? bf2f(((const u16*)src)[loc]) : ((const float*)src)[loc];
        if (kind[s] == 0) f32blk[doff[s] + loc] = fv;
        else bfblk[doff[s] + loc] = isbf ? ((const u16*)src)[loc] : f2bf(fv);
        break;
      }
      base += cnts[s];
    }
  }
  // gene -> bf16 only in the fp32-input world (merged former k_conv_gene)
  if (!isbf) {
    const float2* g2 = (const float2*)in.p[0];
    for (int e = gtid; e < NN * GG / 2; e += gridDim.x * blockDim.x) {
      float2 f = g2[e];
      geneB[e] = (u32)f2bf(f.x) | ((u32)f2bf(f.y) << 16);
    }
  }
}

__device__ __forceinline__ int cell_of(float v) {
  int c = (int)(v * (float)GRES);
  return c < 0 ? 0 : (c > GRES - 1 ? GRES - 1 : c);
}

// ---------------- grid histogram + scan + fill (single block; coords stashed in regs) ------
__global__ __launch_bounds__(1024) void k_grid(const float* __restrict__ coords,
                                               int* __restrict__ gstart,
                                               float4* __restrict__ pts) {
  __shared__ int hist[NCELL];
  __shared__ int part[NCELL];
  int t = threadIdx.x;
  hist[t] = 0;
  __syncthreads();
  float xs[8], ys[8]; int cl[8];
#pragma unroll
  for (int q = 0; q < 8; ++q) {
    int i = t + 1024 * q;
    float2 c = ((const float2*)coords)[i];
    xs[q] = c.x; ys[q] = c.y;
    cl[q] = cell_of(c.y) * GRES + cell_of(c.x);
    atomicAdd(&hist[cl[q]], 1);
  }
  __syncthreads();
  int v = hist[t];
  part[t] = v;
  __syncthreads();
  for (int o = 1; o < NCELL; o <<= 1) {
    int add = 0;
    if (t >= o) add = part[t - o];
    __syncthreads();
    part[t] += add;
    __syncthreads();
  }
  int excl = part[t] - v;
  gstart[t] = excl;
  hist[t] = excl;                 // reuse hist as the fill cursor (LDS atomics)
  if (t == NCELL - 1) gstart[NCELL] = part[t];
  __syncthreads();
#pragma unroll
  for (int q = 0; q < 8; ++q) {
    int i = t + 1024 * q;
    int p = atomicAdd(&hist[cl[q]], 1);
    // z = x*x + y*y with the SAME rounding sequence conv_small used for sq[i] -> bit-identical
    float z = __fadd_rn(__fmul_rn(xs[q], xs[q]), __fmul_rn(ys[q], ys[q]));
    pts[p] = make_float4(xs[q], ys[q], z, __int_as_float(i));
  }
}

// ---------------- KNN top-9 via spatial grid; EXACT u64 keys (d2_bits<<32 | idx) ----------
// d2 replaces d in the key: fp32 sqrt is monotone, so ordering by d2 == ordering by d, and
// the sqrt chain disappears (weight = exp(-d2/2) directly). Comparator stays EXACT -- the
// round-4 failure showed truncated comparators swap neighbors at rank-9 ties (absmax 1.25).
// Degree/count atomics fused at emission (i-side batched into one atomic pair).
__global__ __launch_bounds__(256) void k_knn_grid(const float4* __restrict__ pts,
                                                  const int* __restrict__ gstart,
                                                  const float* __restrict__ coords,
                                                  const float* __restrict__ sq,
                                                  int* __restrict__ eidx, float* __restrict__ ew,
                                                  float* __restrict__ deg, int* __restrict__ cnt) {
  const int w = threadIdx.x >> 6, lane = threadIdx.x & 63;
  const int i = blockIdx.x * 4 + w;
  const float qx = coords[2*i], qy = coords[2*i+1];
  const float sqi = sq[i];
  const int cx = cell_of(qx), cy = cell_of(qy);
  const int x0 = max(cx - 2, 0), x1 = min(cx + 2, GRES - 1);
  const int y0 = max(cy - 2, 0), y1 = min(cy + 2, GRES - 1);

  u64 a0 = ~0ULL, a1 = ~0ULL, a2 = ~0ULL, a3 = ~0ULL, a4 = ~0ULL,
      a5 = ~0ULL, a6 = ~0ULL, a7 = ~0ULL, a8 = ~0ULL;

#define KSTEP(A) { u64 t_ = A; bool p_ = x < t_; A = p_ ? x : t_; x = p_ ? t_ : x; }
  for (int yy = y0; yy <= y1; ++yy) {
    int sbeg = gstart[yy * GRES + x0];
    int send = gstart[yy * GRES + x1 + 1];
    for (int p = sbeg + lane; p < send; p += 64) {
      float4 pt = pts[p];
      float dot = __fmaf_rn(qy, pt.y, __fmul_rn(qx, pt.x));
      float d2  = fmaxf(__fsub_rn(__fadd_rn(sqi, pt.z), __fmul_rn(2.0f, dot)), 0.0f);
      u64 x = ((u64)__float_as_uint(d2) << 32) | (u32)__float_as_int(pt.w);
      KSTEP(a0) KSTEP(a1) KSTEP(a2) KSTEP(a3) KSTEP(a4)
      KSTEP(a5) KSTEP(a6) KSTEP(a7) KSTEP(a8)
    }
  }

  u64 karr[TOPK];
#pragma unroll
  for (int r = 0; r < TOPK; ++r) {
    u64 g = a0;
#pragma unroll
    for (int o = 32; o > 0; o >>= 1) {
      u64 other = __shfl_xor(g, o, 64);
      if (other < g) g = other;
    }
    bool own = (a0 == g);
    a0 = own ? a1 : a0;  a1 = own ? a2 : a1;  a2 = own ? a3 : a2;
    a3 = own ? a4 : a3;  a4 = own ? a5 : a4;  a5 = own ? a6 : a5;
    a6 = own ? a7 : a6;  a7 = own ? a8 : a7;  a8 = own ? ~0ULL : a8;
    karr[r] = g;
  }

  // window-sufficiency: exact iff 9th-NN d2 < (2*cell)^2 = 0.00390625; use conservative 0.0038937
  if (!(__uint_as_float((u32)(karr[TOPK - 1] >> 32)) < 0.0038937f)) {
    a0 = a1 = a2 = a3 = a4 = a5 = a6 = a7 = a8 = ~0ULL;
    const float2* c2 = (const float2*)coords;
    for (int c = 0; c < 128; ++c) {
      int j = c * 64 + lane;
      float2 cjf = c2[j];
      float dot = __fmaf_rn(qy, cjf.y, __fmul_rn(qx, cjf.x));
      float d2  = fmaxf(__fsub_rn(__fadd_rn(sqi, sq[j]), __fmul_rn(2.0f, dot)), 0.0f);
      u64 x = ((u64)__float_as_uint(d2) << 32) | (u32)j;
      KSTEP(a0) KSTEP(a1) KSTEP(a2) KSTEP(a3) KSTEP(a4)
      KSTEP(a5) KSTEP(a6) KSTEP(a7) KSTEP(a8)
    }
#pragma unroll
    for (int r = 0; r < TOPK; ++r) {
      u64 g = a0;
#pragma unroll
      for (int o = 32; o > 0; o >>= 1) {
        u64 other = __shfl_xor(g, o, 64);
        if (other < g) g = other;
      }
      bool own = (a0 == g);
      a0 = own ? a1 : a0;  a1 = own ? a2 : a1;  a2 = own ? a3 : a2;
      a3 = own ? a4 : a3;  a4 = own ? a5 : a4;  a5 = own ? a6 : a5;
      a6 = own ? a7 : a6;  a7 = own ? a8 : a7;  a8 = own ? ~0ULL : a8;
      karr[r] = g;
    }
  }
#undef KSTEP

  if (lane == 0) {
    float hsum = 0.f;
#pragma unroll
    for (int r = 0; r < TOPK; ++r) {
      int j = (int)(karr[r] & 0xffffffffu);
      float d2 = __uint_as_float((u32)(karr[r] >> 32));
      float wgt = (j == i) ? 0.0f : expf(-0.5f * d2);
      eidx[i * TOPK + r] = j;
      ew[i * TOPK + r] = wgt;
      float h = 0.5f * wgt;
      hsum += h;
      atomicAdd(&deg[j], h);
      atomicAdd(&cnt[j], 1);
    }
    atomicAdd(&deg[i], hsum);
    atomicAdd(&cnt[i], TOPK);
  }
}

// ---------------- CSR scan (+ dis from deg) ----------------
__global__ __launch_bounds__(1024) void k_scan(const int* __restrict__ cnt,
                                               const float* __restrict__ deg,
                                               int* __restrict__ rs, int* __restrict__ cur,
                                               float* __restrict__ dis) {
  __shared__ int part[1024];
  int t = threadIdx.x;
  int base = t * 8;
  int loc[8]; int s = 0;
#pragma unroll
  for (int q = 0; q < 8; ++q) { loc[q] = s; s += cnt[base + q]; }
  part[t] = s;
  __syncthreads();
  for (int o = 1; o < 1024; o <<= 1) {
    int v = 0;
    if (t >= o) v = part[t - o];
    __syncthreads();
    part[t] += v;
    __syncthreads();
  }
  int excl = (t == 0) ? 0 : part[t - 1];
#pragma unroll
  for (int q = 0; q < 8; ++q) {
    int val = excl + loc[q];
    rs[base + q] = val;
    cur[base + q] = val;
    dis[base + q] = 1.0f / sqrtf(deg[base + q] + 1e-8f);
  }
  if (t == 1023) rs[NN] = excl + s;
}

__global__ void k_fill(const int* __restrict__ eidx, const float* __restrict__ ew,
                       int* __restrict__ cur, int* __restrict__ ccol, float* __restrict__ cw) {
  int t = blockIdx.x * blockDim.x + threadIdx.x;
  if (t >= NEDGE) return;
  int i = t / TOPK;
  int j = eidx[t] & (NN - 1);
  float h = 0.5f * ew[t];
  int s1 = atomicAdd(&cur[i], 1); ccol[s1] = j; cw[s1] = h;
  int s2 = atomicAdd(&cur[j], 1); ccol[s2] = i; cw[s2] = h;
}

// ====================================================================================
// B-stationary barrier-free MFMA GEMMs (see round-2 notes).
// ====================================================================================

// ---- GEMM1: h = relu(gene@Wg^T + b) + relu(coords-MLP).  512 thr, BM=128, grid (64,8) ----
__global__ __launch_bounds__(512, 4) void k_bgemm0(const void* __restrict__ Araw,
                                                   const u16* __restrict__ Aconv,
                                                   const u16* __restrict__ W,
                                                   const float* __restrict__ bias,
                                                   const float* __restrict__ coords,
                                                   const float* __restrict__ Wc1,
                                                   const float* __restrict__ bc1,
                                                   const int* __restrict__ flag,
                                                   u16* __restrict__ outp) {
  __shared__ u16 Bs[64][BPAD];
  const int tid = threadIdx.x, lane = tid & 63, w = tid >> 6;
  const int quad = lane >> 4, l16 = lane & 15;
  const int row0 = blockIdx.x * 128, col0 = blockIdx.y * 64;
  int flg = *flag;
  const u16* A = flg ? (const u16*)Araw : Aconv;

  // stage B panel: 64 rows x 64 chunks of 8 u16
#pragma unroll
  for (int q = 0; q < 8; ++q) {
    int idx = tid + 512 * q;
    int r = idx >> 6, c = idx & 63;
    *(uint4*)(&Bs[r][c * 8]) = *(const uint4*)(W + (size_t)(col0 + r) * 512 + c * 8);
  }
  __syncthreads();

  f32x4 acc[4];
#pragma unroll
  for (int n = 0; n < 4; ++n) acc[n] = (f32x4){0.f, 0.f, 0.f, 0.f};

  const u16* Ab = A + (size_t)(row0 + w * 16 + l16) * 512 + quad * 8;
#pragma unroll
  for (int kc = 0; kc < 16; ++kc) {
    bf16x8 af = *(const bf16x8*)(Ab + kc * 32);
    bf16x8 bfr[4];
#pragma unroll
    for (int n = 0; n < 4; ++n)
      bfr[n] = *(const bf16x8*)(&Bs[n * 16 + l16][kc * 32 + quad * 8]);
#pragma unroll
    for (int n = 0; n < 4; ++n)
      acc[n] = __builtin_amdgcn_mfma_f32_16x16x32_bf16(af, bfr[n], acc[n], 0, 0, 0);
  }

  __syncthreads();                 // all waves done reading Bs -> reuse as staging tile
  u16* St = &Bs[0][0];             // [128][64]
  {
    int rloc = w * 16 + quad * 4;
    int rbase = row0 + rloc;
    float cx[4], cy[4];
#pragma unroll
    for (int reg = 0; reg < 4; ++reg) { cx[reg] = coords[2 * (rbase + reg)]; cy[reg] = coords[2 * (rbase + reg) + 1]; }
#pragma unroll
    for (int n = 0; n < 4; ++n) {
      int cg = col0 + n * 16 + l16;
      float bval = bias[cg];
      float wc0 = Wc1[2 * cg], wc1 = Wc1[2 * cg + 1], bcv = bc1[cg];
#pragma unroll
      for (int reg = 0; reg < 4; ++reg) {
        float v = acc[n][reg] + bval;
        float hc = cx[reg] * wc0 + cy[reg] * wc1 + bcv;
        v = fmaxf(v, 0.f) + fmaxf(hc, 0.f);
        St[(rloc + reg) * 64 + n * 16 + l16] = f2bf(v);
      }
    }
  }
  __syncthreads();
#pragma unroll
  for (int q = 0; q < 2; ++q) {
    int idx = tid + 512 * q;
    int r = idx >> 3, c = idx & 7;
    *(uint4*)(outp + (size_t)(row0 + r) * 512 + col0 + c * 8) = ((const uint4*)St)[idx];
  }
}

// ---- dual GEMM: hm = h@Wm^T (raw), hs = relu(h@Ws^T + b_self). Wcat = [Wm;Ws] 1024 rows ----
__global__ __launch_bounds__(512, 4) void k_bgemm_dual(const u16* __restrict__ A,
                                                       const u16* __restrict__ Wcat,
                                                       const float* __restrict__ bself,
                                                       u16* __restrict__ hm,
                                                       u16* __restrict__ hs) {
  __shared__ u16 Bs[64][BPAD];
  const int tid = threadIdx.x, lane = tid & 63, w = tid >> 6;
  const int quad = lane >> 4, l16 = lane & 15;
  const int row0 = blockIdx.x * 256, col0 = blockIdx.y * 64;   // col0 in [0,1024)
  const int selfhalf = (col0 >= 512);

#pragma unroll
  for (int q = 0; q < 8; ++q) {
    int idx = tid + 512 * q;
    int r = idx >> 6, c = idx & 63;
    *(uint4*)(&Bs[r][c * 8]) = *(const uint4*)(Wcat + (size_t)(col0 + r) * 512 + c * 8);
  }
  __syncthreads();

  f32x4 acc[2][4];
#pragma unroll
  for (int mr = 0; mr < 2; ++mr)
#pragma unroll
    for (int n = 0; n < 4; ++n) acc[mr][n] = (f32x4){0.f, 0.f, 0.f, 0.f};

  const u16* Ab = A + (size_t)(row0 + w * 32 + l16) * 512 + quad * 8;
#pragma unroll
  for (int kc = 0; kc < 16; ++kc) {
    bf16x8 af0 = *(const bf16x8*)(Ab + kc * 32);
    bf16x8 af1 = *(const bf16x8*)(Ab + 16 * 512 + kc * 32);
    bf16x8 bfr[4];
#pragma unroll
    for (int n = 0; n < 4; ++n)
      bfr[n] = *(const bf16x8*)(&Bs[n * 16 + l16][kc * 32 + quad * 8]);
#pragma unroll
    for (int n = 0; n < 4; ++n) {
      acc[0][n] = __builtin_amdgcn_mfma_f32_16x16x32_bf16(af0, bfr[n], acc[0][n], 0, 0, 0);
      acc[1][n] = __builtin_amdgcn_mfma_f32_16x16x32_bf16(af1, bfr[n], acc[1][n], 0, 0, 0);
    }
  }

  __syncthreads();
  u16* St = &Bs[0][0];             // [256][64]
  const int dcol0 = col0 & 511;
#pragma unroll
  for (int mr = 0; mr < 2; ++mr) {
    int rloc = w * 32 + mr * 16 + quad * 4;
#pragma unroll
    for (int n = 0; n < 4; ++n) {
      int cl = dcol0 + n * 16 + l16;
      float bval = selfhalf ? bself[cl] : 0.f;
#pragma unroll
      for (int reg = 0; reg < 4; ++reg) {
        float v = acc[mr][n][reg];
        if (selfhalf) v = fmaxf(v + bval, 0.f);   // hs = relu(h@Ws^T + b_self)
        St[(rloc + reg) * 64 + n * 16 + l16] = f2bf(v);  // hm raw: bias added post-agg
      }
    }
  }
  __syncthreads();
  u16* dst = selfhalf ? hs : hm;
#pragma unroll
  for (int q = 0; q < 4; ++q) {
    int idx = tid + 512 * q;
    int r = idx >> 3, c = idx & 7;
    *(uint4*)(dst + (size_t)(row0 + r) * 512 + dcol0 + c * 8) = ((const uint4*)St)[idx];
  }
}

// ---- h_final = relu(relu(A_norm@hm + b_msg) + hs)  (SpMV, 4-edge-wide gather) ----
__global__ __launch_bounds__(256) void k_agg2(const int* __restrict__ rs, const int* __restrict__ ccol,
                                              const float* __restrict__ cw, const float* __restrict__ dis,
                                              const u16* __restrict__ hm, const u16* __restrict__ hs,
                                              const float* __restrict__ bmsg, u16* __restrict__ hf) {
  __shared__ float sacc[4][512];
  const int i = blockIdx.x, t = threadIdx.x;
  const int g = t >> 6, l = t & 63;
  const int b = rs[i], e = rs[i + 1];
  float acc[8];
#pragma unroll
  for (int j = 0; j < 8; ++j) acc[j] = 0.f;
  for (int q = b + g; q < e; q += 4) {
    int c = ccol[q];
    float w = cw[q] * dis[c];
    uint4 p = *(const uint4*)(hm + (size_t)c * HH + l * 8);
    acc[0] = fmaf(w, bf2f((u16)(p.x & 0xffff)), acc[0]);
    acc[1] = fmaf(w, bf2f((u16)(p.x >> 16)),    acc[1]);
    acc[2] = fmaf(w, bf2f((u16)(p.y & 0xffff)), acc[2]);
    acc[3] = fmaf(w, bf2f((u16)(p.y >> 16)),    acc[3]);
    acc[4] = fmaf(w, bf2f((u16)(p.z & 0xffff)), acc[4]);
    acc[5] = fmaf(w, bf2f((u16)(p.z >> 16)),    acc[5]);
    acc[6] = fmaf(w, bf2f((u16)(p.w & 0xffff)), acc[6]);
    acc[7] = fmaf(w, bf2f((u16)(p.w >> 16)),    acc[7]);
  }
#pragma unroll
  for (int j = 0; j < 8; ++j) sacc[g][l * 8 + j] = acc[j];
  __syncthreads();
  float di = dis[i];
  int c0 = 2 * t, c1 = 2 * t + 1;
  float s0 = (sacc[0][c0] + sacc[1][c0]) + (sacc[2][c0] + sacc[3][c0]);
  float s1 = (sacc[0][c1] + sacc[1][c1]) + (sacc[2][c1] + sacc[3][c1]);
  float m0 = fmaxf(fmaf(di, s0, bmsg[c0]), 0.f);
  float m1 = fmaxf(fmaf(di, s1, bmsg[c1]), 0.f);
  u32 sp = *(const u32*)(hs + (size_t)i * HH + c0);
  float f0 = fmaxf(m0 + bf2f((u16)(sp & 0xffff)), 0.f);
  float f1 = fmaxf(m1 + bf2f((u16)(sp >> 16)), 0.f);
  u32 packed = (u32)f2bf(f0) | ((u32)f2bf(f1) << 16);
  *(u32*)(hf + (size_t)i * HH + c0) = packed;
}

// ---- GEMM3: out = h_final@Wz^T + bz.  BM=16, 256 thr, grid 512; LDS-staged stores ----
__global__ __launch_bounds__(256) void k_bgemm3(const u16* __restrict__ A,
                                                const u16* __restrict__ W,
                                                const float* __restrict__ bias,
                                                const int* __restrict__ flag,
                                                void* __restrict__ outp) {
  __shared__ u16 Bs[64][BPAD];
  const int tid = threadIdx.x, lane = tid & 63, w = tid >> 6;   // w = n-frag 0..3
  const int quad = lane >> 4, l16 = lane & 15;
  const int row0 = blockIdx.x * 16;
  int flg = *flag;

#pragma unroll
  for (int q = 0; q < 16; ++q) {
    int idx = tid + 256 * q;
    int r = idx >> 6, c = idx & 63;
    *(uint4*)(&Bs[r][c * 8]) = *(const uint4*)(W + (size_t)r * 512 + c * 8);
  }
  __syncthreads();

  f32x4 acc = (f32x4){0.f, 0.f, 0.f, 0.f};
  const u16* Ab = A + (size_t)(row0 + l16) * 512 + quad * 8;
#pragma unroll
  for (int kc = 0; kc < 16; ++kc) {
    bf16x8 af  = *(const bf16x8*)(Ab + kc * 32);
    bf16x8 bfw = *(const bf16x8*)(&Bs[w * 16 + l16][kc * 32 + quad * 8]);
    acc = __builtin_amdgcn_mfma_f32_16x16x32_bf16(af, bfw, acc, 0, 0, 0);
  }

  __syncthreads();
  if (!flg) {
    // fp32-output world: stage [16][64] f32 tile, float4 stores
    float* Stf = (float*)&Bs[0][0];
    float bval = bias[w * 16 + l16];
#pragma unroll
    for (int reg = 0; reg < 4; ++reg)
      Stf[(quad * 4 + reg) * 64 + w * 16 + l16] = acc[reg] + bval;
    __syncthreads();
    int r = tid >> 4, c = tid & 15;
    ((float4*)outp)[(size_t)(row0 + r) * 16 + c] = ((const float4*)Stf)[tid];
    return;
  }

  u16* St = &Bs[0][0];             // [16][64] bf16
  float bval = bias[w * 16 + l16];
#pragma unroll
  for (int reg = 0; reg < 4; ++reg)
    St[(quad * 4 + reg) * 64 + w * 16 + l16] = f2bf(acc[reg] + bval);
  __syncthreads();
  if (tid < 128) {
    int r = tid >> 3, c = tid & 7;
    *(uint4*)((u16*)outp + (size_t)(row0 + r) * 64 + c * 8) = ((const uint4*)St)[tid];
  }
}

extern "C" void kernel_launch(void* const* d_in, const int* in_sizes, int n_in,
                              void* d_out, int out_size, void* d_ws, size_t ws_size,
                              hipStream_t stream) {
  float* ws = (float*)d_ws;
  size_t off = 0;
  auto alloc = [&](size_t n) { size_t o = off; off += (n + 15) & ~(size_t)15; return o; };

  const size_t PLANE = (size_t)NN * HH / 2;

  size_t o_flag  = alloc(16);
  size_t o_f32   = alloc(19520);
  size_t o_bfw   = alloc(409600);
  size_t o_geneB = alloc(PLANE);
  size_t o_Hb    = alloc(PLANE);
  size_t o_Mb    = alloc(PLANE);
  size_t o_sq    = alloc(NN);
  size_t o_deg   = alloc(NN);
  size_t o_dis   = alloc(NN);
  size_t o_cnt   = alloc(NN);
  size_t o_rs    = alloc(NN + 16);
  size_t o_cur   = alloc(NN);
  size_t o_eidx  = alloc(NEDGE);
  size_t o_ew    = alloc(NEDGE);
  size_t o_ccol  = alloc(NNZ);
  size_t o_cw    = alloc(NNZ);
  size_t o_pts   = alloc(NN * 4);
  size_t o_gsta  = alloc(NCELL + 16);
  (void)ws_size;

  int*   flag    = (int*)(ws + o_flag);
  float* f32blk  = ws + o_f32;
  float* coordsF = f32blk + 0;
  float* bg1     = f32blk + 16384;
  float* Wc1f    = f32blk + 16896;
  float* bc1f    = f32blk + 17920;
  float* bmsg    = f32blk + 18432;
  float* bself   = f32blk + 18944;
  float* bz      = f32blk + 19456;
  u16*   bfblk   = (u16*)(ws + o_bfw);
  u16*   WgB     = bfblk + 0;
  u16*   WmB     = bfblk + 262144;   // [Wm;Ws] contiguous 1024x512 starting here
  u16*   WzB     = bfblk + 786432;
  u16*   geneB   = (u16*)(ws + o_geneB);
  u16*   Hb      = (u16*)(ws + o_Hb);
  u16*   Mb      = (u16*)(ws + o_Mb);
  float* sq      = ws + o_sq;
  float* deg     = ws + o_deg;
  float* dis     = ws + o_dis;
  int*   cnt     = (int*)(ws + o_cnt);
  int*   rs      = (int*)(ws + o_rs);
  int*   cur     = (int*)(ws + o_cur);
  int*   eidx    = (int*)(ws + o_eidx);
  float* ew      = ws + o_ew;
  int*   ccol    = (int*)(ws + o_ccol);
  float* cw      = ws + o_cw;
  float4* pts    = (float4*)(ws + o_pts);
  int*   gstart  = (int*)(ws + o_gsta);

  // plane reuse: hm <- geneB plane; hs <- Mb plane; h_final <- Hb plane.
  u16* HM = geneB;
  u16* HS = Mb;
  u16* HF = Hb;

  InPtrs ip;
  for (int s = 0; s < 12; ++s) ip.p[s] = d_in[s];

  k_conv_small<<<512, 256, 0, stream>>>(ip, flag, f32blk, bfblk, deg, cnt, sq, (u32*)geneB);
  k_grid<<<1, 1024, 0, stream>>>(coordsF, gstart, pts);
  k_knn_grid<<<NN / 4, 256, 0, stream>>>(pts, gstart, coordsF, sq, eidx, ew, deg, cnt);
  k_scan<<<1, 1024, 0, stream>>>(cnt, deg, rs, cur, dis);
  k_fill<<<(NEDGE + 255) / 256, 256, 0, stream>>>(eidx, ew, cur, ccol, cw);

  k_bgemm0<<<dim3(64, 8), 512, 0, stream>>>(d_in[0], geneB, WgB, bg1, coordsF, Wc1f, bc1f, flag, Hb);
  k_bgemm_dual<<<dim3(32, 16), 512, 0, stream>>>(Hb, WmB, bself, HM, HS);
  k_agg2<<<NN, 256, 0, stream>>>(rs, ccol, cw, dis, HM, HS, bmsg, HF);
  k_bgemm3<<<512, 256, 0, stream>>>(HF, WzB, bz, flag, d_out);
}